// Round 10
// baseline (41236.273 us; speedup 1.0000x reference)
//
#include <hip/hip_runtime.h>
#include <hip/hip_bf16.h>

#define TSTEPS 512
#define NSTEPS 256          // steps per chunk
#define BATCH  64
#define HDIM   1024
#define NROWS  (TSTEPS*BATCH)   // 32768

typedef __attribute__((ext_vector_type(8))) short bf16x8;
typedef __attribute__((ext_vector_type(4))) float f32x4;

__device__ __forceinline__ unsigned short f2bf(float f){
    unsigned u = __float_as_uint(f);
    u += 0x7fffu + ((u >> 16) & 1u);
    return (unsigned short)(u >> 16);
}
__device__ __forceinline__ float bf2f(unsigned short s){
    return __uint_as_float(((unsigned)s) << 16);
}

// ---------------------------------------------------------------------------
// W [1024][4096] fp32 -> WThi/WTlo [4096][1024] bf16 (transpose + split)
// ---------------------------------------------------------------------------
__global__ __launch_bounds__(256)
void split_transpose_w(const float* __restrict__ W,
                       unsigned short* __restrict__ WThi,
                       unsigned short* __restrict__ WTlo)
{
    __shared__ float tile[32][33];
    const int c0 = blockIdx.x * 32;
    const int k0 = blockIdx.y * 32;
    const int tx = threadIdx.x & 31, ty = threadIdx.x >> 5;
    #pragma unroll
    for (int r=0;r<4;++r)
        tile[ty + r*8][tx] = W[(size_t)(k0 + ty + r*8)*4096 + c0 + tx];
    __syncthreads();
    #pragma unroll
    for (int r=0;r<4;++r){
        float v = tile[tx][ty + r*8];
        unsigned short hi = f2bf(v);
        unsigned short lo = f2bf(v - bf2f(hi));
        WThi[(size_t)(c0 + ty + r*8)*1024 + k0 + tx] = hi;
        WTlo[(size_t)(c0 + ty + r*8)*1024 + k0 + tx] = lo;
    }
}

// ---------------------------------------------------------------------------
// W_hh [1024][4096] fp32 -> WhhR [256][1024][16] fp32, block-contiguous
// ---------------------------------------------------------------------------
__global__ __launch_bounds__(256)
void reorder_whh(const float* __restrict__ W, float* __restrict__ Wr)
{
    const int bid = blockIdx.x;
    const int tid = threadIdx.x;
    #pragma unroll
    for (int kk=0; kk<4; ++kk){
        const int k = tid*4 + kk;
        float* dst = Wr + ((size_t)bid*1024 + k)*16;
        #pragma unroll
        for (int j=0;j<16;++j)
            dst[j] = W[(size_t)k*4096 + (j>>2)*1024 + bid*4 + (j&3)];
    }
}

// ---------------------------------------------------------------------------
// Split-bf16 MFMA GEMM over one 16384-row chunk (proven structure, bf16 out):
//   gp[t][bid][b][j] = bf16( sum_k A[row][k]*W[k][col] + bias[col] )
// ---------------------------------------------------------------------------
__global__ __launch_bounds__(256)
void gemm_xw_split(const float* __restrict__ A,
                   const unsigned short* __restrict__ BThi,
                   const unsigned short* __restrict__ BTlo,
                   const float* __restrict__ bias, unsigned short* __restrict__ gp)
{
    __shared__ __align__(16) unsigned short Ahi[128*32];
    __shared__ __align__(16) unsigned short Alo[128*32];
    __shared__ __align__(16) unsigned short Bhi[128*32];
    __shared__ __align__(16) unsigned short Blo[128*32];

    const int tid = threadIdx.x;
    const int w = tid >> 6, l = tid & 63;
    const int bx = blockIdx.x & 31, by = blockIdx.x >> 5;
    const int row0 = by*128, col0 = bx*128;
    const int wrow = (w>>1)*64, wcol = (w&1)*64;

    const int srow  = l >> 2;
    const int skoff = (l & 3) * 8;

    const int arow  = tid >> 1;
    const int akoff = (tid & 1) * 16;
    const float* aptr = A + (size_t)(row0 + arow)*1024 + akoff;

    f32x4 acc[4][4];
    #pragma unroll
    for (int m=0;m<4;++m)
        #pragma unroll
        for (int n=0;n<4;++n)
            acc[m][n] = (f32x4){0.f,0.f,0.f,0.f};

    for (int k0=0; k0<1024; k0+=32){
        #pragma unroll
        for (int c=0;c<2;++c){
            const int i = w*2 + c;
            const unsigned short* gh = BThi + (size_t)(col0 + i*16 + srow)*1024 + k0 + skoff;
            const unsigned short* gl = BTlo + (size_t)(col0 + i*16 + srow)*1024 + k0 + skoff;
            __builtin_amdgcn_global_load_lds((const __attribute__((address_space(1))) void*)gh,
                (__attribute__((address_space(3))) void*)(Bhi + i*512), 16, 0, 0);
            __builtin_amdgcn_global_load_lds((const __attribute__((address_space(1))) void*)gl,
                (__attribute__((address_space(3))) void*)(Blo + i*512), 16, 0, 0);
        }
        {
            float4 x0 = *reinterpret_cast<const float4*>(aptr + k0);
            float4 x1 = *reinterpret_cast<const float4*>(aptr + k0 + 4);
            float4 x2 = *reinterpret_cast<const float4*>(aptr + k0 + 8);
            float4 x3 = *reinterpret_cast<const float4*>(aptr + k0 + 12);
            float xs[16] = {x0.x,x0.y,x0.z,x0.w, x1.x,x1.y,x1.z,x1.w,
                            x2.x,x2.y,x2.z,x2.w, x3.x,x3.y,x3.z,x3.w};
            unsigned short hs[16], ls[16];
            #pragma unroll
            for (int e=0;e<16;++e){
                hs[e] = f2bf(xs[e]);
                ls[e] = f2bf(xs[e] - bf2f(hs[e]));
            }
            #pragma unroll
            for (int q=0;q<4;++q){
                ushort4 h4; h4.x=hs[q*4]; h4.y=hs[q*4+1]; h4.z=hs[q*4+2]; h4.w=hs[q*4+3];
                ushort4 l4; l4.x=ls[q*4]; l4.y=ls[q*4+1]; l4.z=ls[q*4+2]; l4.w=ls[q*4+3];
                *reinterpret_cast<ushort4*>(&Ahi[arow*32 + akoff + q*4]) = h4;
                *reinterpret_cast<ushort4*>(&Alo[arow*32 + akoff + q*4]) = l4;
            }
        }
        __syncthreads();
        bf16x8 afh[4], afl[4], bfh[4], bfl[4];
        #pragma unroll
        for (int m=0;m<4;++m){
            const int off = (wrow + m*16 + (l&15))*32 + (l>>4)*8;
            afh[m] = *reinterpret_cast<const bf16x8*>(&Ahi[off]);
            afl[m] = *reinterpret_cast<const bf16x8*>(&Alo[off]);
        }
        #pragma unroll
        for (int n=0;n<4;++n){
            const int off = (wcol + n*16 + (l&15))*32 + (l>>4)*8;
            bfh[n] = *reinterpret_cast<const bf16x8*>(&Bhi[off]);
            bfl[n] = *reinterpret_cast<const bf16x8*>(&Blo[off]);
        }
        #pragma unroll
        for (int m=0;m<4;++m)
            #pragma unroll
            for (int n=0;n<4;++n){
                acc[m][n] = __builtin_amdgcn_mfma_f32_16x16x32_bf16(afh[m], bfh[n], acc[m][n], 0,0,0);
                acc[m][n] = __builtin_amdgcn_mfma_f32_16x16x32_bf16(afl[m], bfh[n], acc[m][n], 0,0,0);
                acc[m][n] = __builtin_amdgcn_mfma_f32_16x16x32_bf16(afh[m], bfl[n], acc[m][n], 0,0,0);
            }
        __syncthreads();
    }

    #pragma unroll
    for (int n=0;n<4;++n){
        const int n_g = col0 + wcol + n*16 + (l&15);
        const float bv = bias[n_g];
        const int g = n_g >> 10, hcol = n_g & 1023;
        const int bid = hcol >> 2, hj = hcol & 3;
        #pragma unroll
        for (int m=0;m<4;++m){
            #pragma unroll
            for (int r=0;r<4;++r){
                const int m_g = row0 + wrow + m*16 + (l>>4)*4 + r;
                const int t = m_g >> 6, b = m_g & 63;
                gp[(((size_t)t*256 + bid)*64 + b)*16 + g*4 + hj] = f2bf(acc[m][n][r] + bv);
            }
        }
    }
}

// ---------------------------------------------------------------------------
// Dataflow recurrence over one 256-step chunk — fp32 arithmetic (r9 body),
// NO grid barrier. Per-(step,block) flags:
//   producer: h-swaps (returning, 64-bit) -> syncthreads (vmcnt drained)
//             -> tid0 flag-swap flags[t][bidx]=1
//   consumer wave w at step t: poll the 64 flags of its K-range producers
//             (overlapped with xW staging), then plain-load ring slot t-1
//             (fresh addresses -> no stale L2; chunk kernel boundary handles
//              slot reuse across chunks).
// Block owns h-cols [bidx*4, bidx*4+4). c-state in register, ctg across chunks.
// ---------------------------------------------------------------------------
__global__ __launch_bounds__(256)
void lstm_flow(const unsigned short* __restrict__ gp, const float* __restrict__ WhhR,
               float* __restrict__ out, float* __restrict__ ring,
               float* __restrict__ ctg, float* __restrict__ hn, float* __restrict__ cn,
               unsigned int* __restrict__ flags, int first, int last)
{
    __shared__ float Wlds[1024*16];        // 64 KB [k][j]
    __shared__ float hstage[4][2][2048];   // 64 KB per-wave dbuf [32k][64b]
    __shared__ float pacc[4][64*17];       // padded partial gates [b][j]
    __shared__ float xwlds[64*17];         // padded xW slice [b][j]
    __shared__ float hout[256];            // h_new [b*4+hj]

    const int tid  = threadIdx.x;
    const int bidx = blockIdx.x;
    const int w = tid >> 6, l = tid & 63;

    {   // stage W_hh slice once per chunk: 16 x global_load_lds(16B)
        const float* base = WhhR + (size_t)bidx*16384;
        #pragma unroll
        for (int i=0;i<16;++i){
            const float* s = base + i*1024 + w*256 + l*4;
            __builtin_amdgcn_global_load_lds((const __attribute__((address_space(1))) void*)s,
                (__attribute__((address_space(3))) void*)(Wlds + i*1024 + w*256), 16, 0, 0);
        }
    }
    float creg = first ? 0.f : ctg[bidx*256 + tid];

    const int c0 = (l & 3) << 2;
    const int b0 = (l >> 2) << 2;
    const int kbase = w << 8;
    const int bq = tid & 63;
    const int hj = tid >> 6;

    __syncthreads();   // Wlds staged (drains global_load_lds)

    for (int t=0; t<NSTEPS; ++t){
        // --- issue flag polls for our 64 producers (overlap w/ xW staging) ---
        unsigned fval = 1;
        unsigned int* fb = nullptr;
        if (t > 0){
            fb = flags + (size_t)(t-1)*256 + w*64;
            fval = __hip_atomic_load(&fb[l], __ATOMIC_RELAXED, __HIP_MEMORY_SCOPE_AGENT);
        }

        {   // xW[t] slice (bf16) -> xwlds (padded [b][j], stride 17)
            ushort4 v = *reinterpret_cast<const ushort4*>(gp + ((size_t)t*256 + bidx)*1024 + tid*4);
            const int b = tid >> 2, j0 = (tid & 3)*4;
            float* xp = &xwlds[b*17 + j0];
            xp[0]=bf2f(v.x); xp[1]=bf2f(v.y); xp[2]=bf2f(v.z); xp[3]=bf2f(v.w);
        }

        if (t > 0){   // wait for all 64 producers of this wave's K-range
            while (__any(fval == 0)){
                __builtin_amdgcn_s_sleep(1);
                if (fval == 0)
                    fval = __hip_atomic_load(&fb[l], __ATOMIC_RELAXED, __HIP_MEMORY_SCOPE_AGENT);
            }
            asm volatile("" ::: "memory");   // no hoisting ring loads above
        }

        const int rs = (t > 0) ? (t-1) : (first ? 256 : NSTEPS-1);
        const float* hc = ring + (size_t)rs*65536 + (size_t)kbase*64;
        float4 pre[8];
        #pragma unroll
        for (int it=0;it<8;++it)
            pre[it] = *reinterpret_cast<const float4*>(hc + it*256 + l*4);
        #pragma unroll
        for (int it=0;it<8;++it)
            *reinterpret_cast<float4*>(&hstage[w][0][it*256 + l*4]) = pre[it];

        float acc[4][4];
        #pragma unroll
        for (int i2=0;i2<4;++i2){acc[i2][0]=0.f;acc[i2][1]=0.f;acc[i2][2]=0.f;acc[i2][3]=0.f;}

        for (int sc=0; sc<8; ++sc){
            if (sc < 7){
                const float* s2 = hc + (size_t)(sc+1)*2048;
                #pragma unroll
                for (int it=0;it<8;++it)
                    pre[it] = *reinterpret_cast<const float4*>(s2 + it*256 + l*4);
            }
            const float* hs = hstage[w][sc&1];
            const float* wl = &Wlds[(size_t)(kbase + sc*32)*16];
            #pragma unroll
            for (int kk=0; kk<32; ++kk){
                float4 hv = *reinterpret_cast<const float4*>(&hs[kk*64 + b0]);
                float4 wv = *reinterpret_cast<const float4*>(&wl[kk*16 + c0]);
                acc[0][0]+=hv.x*wv.x; acc[0][1]+=hv.x*wv.y; acc[0][2]+=hv.x*wv.z; acc[0][3]+=hv.x*wv.w;
                acc[1][0]+=hv.y*wv.x; acc[1][1]+=hv.y*wv.y; acc[1][2]+=hv.y*wv.z; acc[1][3]+=hv.y*wv.w;
                acc[2][0]+=hv.z*wv.x; acc[2][1]+=hv.z*wv.y; acc[2][2]+=hv.z*wv.z; acc[2][3]+=hv.z*wv.w;
                acc[3][0]+=hv.w*wv.x; acc[3][1]+=hv.w*wv.y; acc[3][2]+=hv.w*wv.z; acc[3][3]+=hv.w*wv.w;
            }
            if (sc < 7){
                float* d = hstage[w][(sc+1)&1];
                #pragma unroll
                for (int it=0;it<8;++it)
                    *reinterpret_cast<float4*>(&d[it*256 + l*4]) = pre[it];
            }
        }
        #pragma unroll
        for (int bi=0;bi<4;++bi){
            float* pp = &pacc[w][(b0+bi)*17 + c0];
            pp[0]=acc[bi][0]; pp[1]=acc[bi][1]; pp[2]=acc[bi][2]; pp[3]=acc[bi][3];
        }
        __syncthreads();

        {   // phase C: one thread per (batch, h-col)
            float gs[4];
            #pragma unroll
            for (int g=0; g<4; ++g){
                const int idx = bq*17 + g*4 + hj;
                gs[g] = xwlds[idx] + pacc[0][idx] + pacc[1][idx] + pacc[2][idx] + pacc[3][idx];
            }
            float ig = 1.f/(1.f + __expf(-gs[0]));
            float fg = 1.f/(1.f + __expf(-gs[1]));
            float gg = tanhf(gs[2]);
            float og = 1.f/(1.f + __expf(-gs[3]));
            float c_new = fg * creg + ig * gg;
            float h_new = og * tanhf(c_new);
            creg = c_new;
            hout[bq*4 + hj] = h_new;
            if (last && t == NSTEPS-1){
                const int hcolg = bidx*4 + hj;
                hn[(size_t)bq*1024 + hcolg] = h_new;
                cn[(size_t)bq*1024 + hcolg] = c_new;
            }
        }
        __syncthreads();

        {   // publish h[t]: 128 x 64-bit returning swaps (ack == at L3)
            float* ringw = ring + (size_t)t*65536;
            if (tid < 128){
                const int coll = tid & 3;
                const int b0p  = (tid >> 2) << 1;
                float v0 = hout[b0p*4 + coll];
                float v1 = hout[(b0p+1)*4 + coll];
                unsigned long long pk =
                    ((unsigned long long)__float_as_uint(v1) << 32) | __float_as_uint(v0);
                unsigned long long old = __hip_atomic_exchange(
                    reinterpret_cast<unsigned long long*>(ringw + (bidx*4 + coll)*64 + b0p),
                    pk, __ATOMIC_RELAXED, __HIP_MEMORY_SCOPE_AGENT);
                asm volatile("" :: "v"(old));
            }
            if (tid < 64){
                float4 hv = *reinterpret_cast<const float4*>(&hout[tid*4]);
                *reinterpret_cast<float4*>(&out[(size_t)t*65536 + (size_t)tid*1024 + bidx*4]) = hv;
            }
        }
        __syncthreads();   // all waves' swaps drained (vmcnt) before flag

        if (tid == 0){     // flag: step t of this block is fully at L3
            unsigned int old = __hip_atomic_exchange(&flags[(size_t)t*256 + bidx], 1u,
                                   __ATOMIC_RELAXED, __HIP_MEMORY_SCOPE_AGENT);
            asm volatile("" :: "v"(old));
        }
    }
    ctg[bidx*256 + tid] = creg;
}

// ---------------------------------------------------------------------------
extern "C" void kernel_launch(void* const* d_in, const int* in_sizes, int n_in,
                              void* d_out, int out_size, void* d_ws, size_t ws_size,
                              hipStream_t stream)
{
    const float* x    = (const float*)d_in[0];
    const float* Wih0 = (const float*)d_in[1];
    const float* Whh0 = (const float*)d_in[2];
    const float* b0   = (const float*)d_in[3];
    const float* Wih1 = (const float*)d_in[4];
    const float* Whh1 = (const float*)d_in[5];
    const float* b1   = (const float*)d_in[6];

    float* out1 = (float*)d_out;
    float* hn   = out1 + (size_t)NROWS*HDIM;      // [2][64][1024]
    float* cn   = hn + 2*BATCH*HDIM;

    // layer-0 output scratch aliases out1 (safe: each out0 chunk is consumed
    // by the layer-1 GEMM before the layer-1 steps overwrite it).
    float* out0 = out1;

    char* wsb = (char*)d_ws;
    unsigned short* gp    = (unsigned short*)wsb;                      // 134,217,728 B
    unsigned short* WThi0 = (unsigned short*)(wsb + 134217728ull);     //   8,388,608
    unsigned short* WTlo0 = (unsigned short*)(wsb + 142606336ull);     //   8,388,608
    unsigned short* WThi1 = (unsigned short*)(wsb + 150994944ull);     //   8,388,608
    unsigned short* WTlo1 = (unsigned short*)(wsb + 159383552ull);     //   8,388,608
    float*          Whh0r = (float*)(wsb + 167772160ull);              //  16,777,216
    float*          Whh1r = (float*)(wsb + 184549376ull);              //  16,777,216
    float*          ring  = (float*)(wsb + 201326592ull);              //  67,371,008 (257 slots)
    float*          ctg   = (float*)(wsb + 268697600ull);              //     262,144
    unsigned int*   flags = (unsigned int*)(wsb + 268959744ull);       //   1,048,576 (4 regions)

    hipMemsetAsync(flags, 0, 4*262144, stream);                    // 4 chunk flag regions
    hipMemsetAsync(ring + (size_t)256*65536, 0, 262144, stream);   // init slot h_{-1}=0
    split_transpose_w<<<dim3(128,32),256,0,stream>>>(Wih0, WThi0, WTlo0);
    split_transpose_w<<<dim3(128,32),256,0,stream>>>(Wih1, WThi1, WTlo1);
    reorder_whh<<<256,256,0,stream>>>(Whh0, Whh0r);
    reorder_whh<<<256,256,0,stream>>>(Whh1, Whh1r);

    const float*          Ain [2] = {x, out0};
    const unsigned short* Whi [2] = {WThi0, WThi1};
    const unsigned short* Wlo [2] = {WTlo0, WTlo1};
    const float*          bia [2] = {b0, b1};
    const float*          whr [2] = {Whh0r, Whh1r};
    float*                outp[2] = {out0, out1};

    for (int layer=0; layer<2; ++layer){
        float* hnL = hn + (size_t)layer*BATCH*HDIM;
        float* cnL = cn + (size_t)layer*BATCH*HDIM;
        for (int chunk=0; chunk<2; ++chunk){
            gemm_xw_split<<<4096,256,0,stream>>>(
                Ain[layer] + (size_t)chunk*NSTEPS*BATCH*HDIM,
                Whi[layer], Wlo[layer], bia[layer], gp);

            const unsigned short* gpc = gp;
            const float* wh = whr[layer];
            float* op = outp[layer] + (size_t)chunk*NSTEPS*BATCH*HDIM;
            float* rg = ring; float* cg_ = ctg;
            unsigned int* fl = flags + (size_t)(layer*2 + chunk)*65536;
            int first = (chunk == 0), last = (chunk == 1);
            void* args[10] = {(void*)&gpc, (void*)&wh, (void*)&op, (void*)&rg,
                              (void*)&cg_, (void*)&hnL, (void*)&cnL,
                              (void*)&fl, (void*)&first, (void*)&last};
            hipLaunchCooperativeKernel(reinterpret_cast<void*>(&lstm_flow),
                                       dim3(256), dim3(256), args, 0, stream);
        }
    }
}

// Round 11
// 35291.647 us; speedup vs baseline: 1.1684x; 1.1684x over previous
//
#include <hip/hip_runtime.h>
#include <hip/hip_bf16.h>

#define TSTEPS 512
#define NSTEPS 256          // steps per chunk
#define BATCH  64
#define HDIM   1024
#define NROWS  (TSTEPS*BATCH)   // 32768

typedef __attribute__((ext_vector_type(8))) short bf16x8;
typedef __attribute__((ext_vector_type(4))) float f32x4;

__device__ __forceinline__ unsigned short f2bf(float f){
    unsigned u = __float_as_uint(f);
    u += 0x7fffu + ((u >> 16) & 1u);
    return (unsigned short)(u >> 16);
}
__device__ __forceinline__ float bf2f(unsigned short s){
    return __uint_as_float(((unsigned)s) << 16);
}

// ---------------------------------------------------------------------------
// Contention-free broadcast grid barrier.
// r9 semantics (proven), new topology: every polled/written word sits on its
// OWN 128B cache line, so no two agents ever contend on a line.
//   arrival slots: region[b*32],        b=0..255  (block b's private line)
//   release words: region[8192 + b*32], b=0..255  (block b's private line)
// Epochs monotonic per region; one region per kernel instance.
// h data coherence: returning atomic swaps (ack == at L3) + fresh-address
// plain reads; __syncthreads drains each wave's vmcnt before arrival.
// ---------------------------------------------------------------------------
__device__ __forceinline__ void gridbar(unsigned int* region, unsigned int epoch){
    unsigned int* slots = region;
    unsigned int* rel   = region + 8192;
    __syncthreads();    // all waves' vmem (incl. h swaps) acked at L3
    if (blockIdx.x == 0){
        const int i = threadIdx.x;
        if (i > 0){     // poll slot i (blocks 1..255), one private line each
            while (__hip_atomic_load(&slots[i*32], __ATOMIC_RELAXED, __HIP_MEMORY_SCOPE_AGENT) < epoch)
                __builtin_amdgcn_s_sleep(2);
        }
        __syncthreads();
        {   // broadcast: 256 private release words (parallel returning swaps)
            unsigned int old = __hip_atomic_exchange(&rel[i*32], epoch,
                                   __ATOMIC_RELAXED, __HIP_MEMORY_SCOPE_AGENT);
            asm volatile("" :: "v"(old));
        }
    } else {
        if (threadIdx.x == 0){
            unsigned int old = __hip_atomic_exchange(&slots[blockIdx.x*32], epoch,
                                   __ATOMIC_RELAXED, __HIP_MEMORY_SCOPE_AGENT);
            asm volatile("" :: "v"(old));   // returning form (ack == visible)
            while (__hip_atomic_load(&rel[blockIdx.x*32], __ATOMIC_RELAXED, __HIP_MEMORY_SCOPE_AGENT) < epoch)
                __builtin_amdgcn_s_sleep(2);
        }
        __syncthreads();
    }
    asm volatile("" ::: "memory");  // compiler: no hoisting ring loads above
}

// ---------------------------------------------------------------------------
// W [1024][4096] fp32 -> WThi/WTlo [4096][1024] bf16 (transpose + split)
// ---------------------------------------------------------------------------
__global__ __launch_bounds__(256)
void split_transpose_w(const float* __restrict__ W,
                       unsigned short* __restrict__ WThi,
                       unsigned short* __restrict__ WTlo)
{
    __shared__ float tile[32][33];
    const int c0 = blockIdx.x * 32;
    const int k0 = blockIdx.y * 32;
    const int tx = threadIdx.x & 31, ty = threadIdx.x >> 5;
    #pragma unroll
    for (int r=0;r<4;++r)
        tile[ty + r*8][tx] = W[(size_t)(k0 + ty + r*8)*4096 + c0 + tx];
    __syncthreads();
    #pragma unroll
    for (int r=0;r<4;++r){
        float v = tile[tx][ty + r*8];
        unsigned short hi = f2bf(v);
        unsigned short lo = f2bf(v - bf2f(hi));
        WThi[(size_t)(c0 + ty + r*8)*1024 + k0 + tx] = hi;
        WTlo[(size_t)(c0 + ty + r*8)*1024 + k0 + tx] = lo;
    }
}

// ---------------------------------------------------------------------------
// W_hh [1024][4096] fp32 -> WhhR [256][1024][16] fp32, block-contiguous
// ---------------------------------------------------------------------------
__global__ __launch_bounds__(256)
void reorder_whh(const float* __restrict__ W, float* __restrict__ Wr)
{
    const int bid = blockIdx.x;
    const int tid = threadIdx.x;
    #pragma unroll
    for (int kk=0; kk<4; ++kk){
        const int k = tid*4 + kk;
        float* dst = Wr + ((size_t)bid*1024 + k)*16;
        #pragma unroll
        for (int j=0;j<16;++j)
            dst[j] = W[(size_t)k*4096 + (j>>2)*1024 + bid*4 + (j&3)];
    }
}

// ---------------------------------------------------------------------------
// Split-bf16 MFMA GEMM over one 16384-row chunk (proven structure, bf16 out):
//   gp[t][bid][b][j] = bf16( sum_k A[row][k]*W[k][col] + bias[col] )
// ---------------------------------------------------------------------------
__global__ __launch_bounds__(256)
void gemm_xw_split(const float* __restrict__ A,
                   const unsigned short* __restrict__ BThi,
                   const unsigned short* __restrict__ BTlo,
                   const float* __restrict__ bias, unsigned short* __restrict__ gp)
{
    __shared__ __align__(16) unsigned short Ahi[128*32];
    __shared__ __align__(16) unsigned short Alo[128*32];
    __shared__ __align__(16) unsigned short Bhi[128*32];
    __shared__ __align__(16) unsigned short Blo[128*32];

    const int tid = threadIdx.x;
    const int w = tid >> 6, l = tid & 63;
    const int bx = blockIdx.x & 31, by = blockIdx.x >> 5;
    const int row0 = by*128, col0 = bx*128;
    const int wrow = (w>>1)*64, wcol = (w&1)*64;

    const int srow  = l >> 2;
    const int skoff = (l & 3) * 8;

    const int arow  = tid >> 1;
    const int akoff = (tid & 1) * 16;
    const float* aptr = A + (size_t)(row0 + arow)*1024 + akoff;

    f32x4 acc[4][4];
    #pragma unroll
    for (int m=0;m<4;++m)
        #pragma unroll
        for (int n=0;n<4;++n)
            acc[m][n] = (f32x4){0.f,0.f,0.f,0.f};

    for (int k0=0; k0<1024; k0+=32){
        #pragma unroll
        for (int c=0;c<2;++c){
            const int i = w*2 + c;
            const unsigned short* gh = BThi + (size_t)(col0 + i*16 + srow)*1024 + k0 + skoff;
            const unsigned short* gl = BTlo + (size_t)(col0 + i*16 + srow)*1024 + k0 + skoff;
            __builtin_amdgcn_global_load_lds((const __attribute__((address_space(1))) void*)gh,
                (__attribute__((address_space(3))) void*)(Bhi + i*512), 16, 0, 0);
            __builtin_amdgcn_global_load_lds((const __attribute__((address_space(1))) void*)gl,
                (__attribute__((address_space(3))) void*)(Blo + i*512), 16, 0, 0);
        }
        {
            float4 x0 = *reinterpret_cast<const float4*>(aptr + k0);
            float4 x1 = *reinterpret_cast<const float4*>(aptr + k0 + 4);
            float4 x2 = *reinterpret_cast<const float4*>(aptr + k0 + 8);
            float4 x3 = *reinterpret_cast<const float4*>(aptr + k0 + 12);
            float xs[16] = {x0.x,x0.y,x0.z,x0.w, x1.x,x1.y,x1.z,x1.w,
                            x2.x,x2.y,x2.z,x2.w, x3.x,x3.y,x3.z,x3.w};
            unsigned short hs[16], ls[16];
            #pragma unroll
            for (int e=0;e<16;++e){
                hs[e] = f2bf(xs[e]);
                ls[e] = f2bf(xs[e] - bf2f(hs[e]));
            }
            #pragma unroll
            for (int q=0;q<4;++q){
                ushort4 h4; h4.x=hs[q*4]; h4.y=hs[q*4+1]; h4.z=hs[q*4+2]; h4.w=hs[q*4+3];
                ushort4 l4; l4.x=ls[q*4]; l4.y=ls[q*4+1]; l4.z=ls[q*4+2]; l4.w=ls[q*4+3];
                *reinterpret_cast<ushort4*>(&Ahi[arow*32 + akoff + q*4]) = h4;
                *reinterpret_cast<ushort4*>(&Alo[arow*32 + akoff + q*4]) = l4;
            }
        }
        __syncthreads();
        bf16x8 afh[4], afl[4], bfh[4], bfl[4];
        #pragma unroll
        for (int m=0;m<4;++m){
            const int off = (wrow + m*16 + (l&15))*32 + (l>>4)*8;
            afh[m] = *reinterpret_cast<const bf16x8*>(&Ahi[off]);
            afl[m] = *reinterpret_cast<const bf16x8*>(&Alo[off]);
        }
        #pragma unroll
        for (int n=0;n<4;++n){
            const int off = (wcol + n*16 + (l&15))*32 + (l>>4)*8;
            bfh[n] = *reinterpret_cast<const bf16x8*>(&Bhi[off]);
            bfl[n] = *reinterpret_cast<const bf16x8*>(&Blo[off]);
        }
        #pragma unroll
        for (int m=0;m<4;++m)
            #pragma unroll
            for (int n=0;n<4;++n){
                acc[m][n] = __builtin_amdgcn_mfma_f32_16x16x32_bf16(afh[m], bfh[n], acc[m][n], 0,0,0);
                acc[m][n] = __builtin_amdgcn_mfma_f32_16x16x32_bf16(afl[m], bfh[n], acc[m][n], 0,0,0);
                acc[m][n] = __builtin_amdgcn_mfma_f32_16x16x32_bf16(afh[m], bfl[n], acc[m][n], 0,0,0);
            }
        __syncthreads();
    }

    #pragma unroll
    for (int n=0;n<4;++n){
        const int n_g = col0 + wcol + n*16 + (l&15);
        const float bv = bias[n_g];
        const int g = n_g >> 10, hcol = n_g & 1023;
        const int bid = hcol >> 2, hj = hcol & 3;
        #pragma unroll
        for (int m=0;m<4;++m){
            #pragma unroll
            for (int r=0;r<4;++r){
                const int m_g = row0 + wrow + m*16 + (l>>4)*4 + r;
                const int t = m_g >> 6, b = m_g & 63;
                gp[(((size_t)t*256 + bid)*64 + b)*16 + g*4 + hj] = f2bf(acc[m][n][r] + bv);
            }
        }
    }
}

// ---------------------------------------------------------------------------
// Persistent recurrence over one 256-step chunk — fp32 arithmetic (r9 body,
// unchanged), W_hh resident in LDS, h exchanged through a 257-slot ring:
//   write slot t via returning 64-bit atomic swaps (ack == at coherence point)
//   read  slot t-1 via PLAIN loads (first touch per kernel instance -> fresh)
// Block owns h-cols [bidx*4, bidx*4+4). c-state in register, ctg across chunks.
// ---------------------------------------------------------------------------
__global__ __launch_bounds__(256)
void lstm_ring(const unsigned short* __restrict__ gp, const float* __restrict__ WhhR,
               float* __restrict__ out, float* __restrict__ ring,
               float* __restrict__ ctg, float* __restrict__ hn, float* __restrict__ cn,
               unsigned int* __restrict__ bar, int first, int last)
{
    __shared__ float Wlds[1024*16];        // 64 KB [k][j]
    __shared__ float hstage[4][2][2048];   // 64 KB per-wave dbuf [32k][64b]
    __shared__ float pacc[4][64*17];       // padded partial gates [b][j]
    __shared__ float xwlds[64*17];         // padded xW slice [b][j]
    __shared__ float hout[256];            // h_new [b*4+hj]

    const int tid  = threadIdx.x;
    const int bidx = blockIdx.x;
    const int w = tid >> 6, l = tid & 63;

    {   // stage W_hh slice once per chunk: 16 x global_load_lds(16B)
        const float* base = WhhR + (size_t)bidx*16384;
        #pragma unroll
        for (int i=0;i<16;++i){
            const float* s = base + i*1024 + w*256 + l*4;
            __builtin_amdgcn_global_load_lds((const __attribute__((address_space(1))) void*)s,
                (__attribute__((address_space(3))) void*)(Wlds + i*1024 + w*256), 16, 0, 0);
        }
    }
    float creg = first ? 0.f : ctg[bidx*256 + tid];
    if (first){   // zero slot 256 (h_{-1}) for our columns, returning swaps
        const int colg = bidx*4 + (tid>>6);
        unsigned int old = __hip_atomic_exchange(
            (unsigned int*)(ring + (size_t)256*65536 + colg*64 + (tid&63)),
            0u, __ATOMIC_RELAXED, __HIP_MEMORY_SCOPE_AGENT);
        asm volatile("" :: "v"(old));
    }
    gridbar(bar, 1);   // zero-slot at L3 + W LDS staged (syncthreads drains)

    const int c0 = (l & 3) << 2;
    const int b0 = (l >> 2) << 2;
    const int kbase = w << 8;
    const int bq = tid & 63;
    const int hj = tid >> 6;

    for (int t=0; t<NSTEPS; ++t){
        {   // xW[t] slice (bf16) -> xwlds (padded [b][j], stride 17)
            ushort4 v = *reinterpret_cast<const ushort4*>(gp + ((size_t)t*256 + bidx)*1024 + tid*4);
            const int b = tid >> 2, j0 = (tid & 3)*4;
            float* xp = &xwlds[b*17 + j0];
            xp[0]=bf2f(v.x); xp[1]=bf2f(v.y); xp[2]=bf2f(v.z); xp[3]=bf2f(v.w);
        }

        const int rs = (t > 0) ? (t-1) : (first ? 256 : NSTEPS-1);
        const float* hc = ring + (size_t)rs*65536 + (size_t)kbase*64;
        float4 pre[8];
        #pragma unroll
        for (int it=0;it<8;++it)
            pre[it] = *reinterpret_cast<const float4*>(hc + it*256 + l*4);
        #pragma unroll
        for (int it=0;it<8;++it)
            *reinterpret_cast<float4*>(&hstage[w][0][it*256 + l*4]) = pre[it];

        float acc[4][4];
        #pragma unroll
        for (int i2=0;i2<4;++i2){acc[i2][0]=0.f;acc[i2][1]=0.f;acc[i2][2]=0.f;acc[i2][3]=0.f;}

        for (int sc=0; sc<8; ++sc){
            if (sc < 7){
                const float* s2 = hc + (size_t)(sc+1)*2048;
                #pragma unroll
                for (int it=0;it<8;++it)
                    pre[it] = *reinterpret_cast<const float4*>(s2 + it*256 + l*4);
            }
            const float* hs = hstage[w][sc&1];
            const float* wl = &Wlds[(size_t)(kbase + sc*32)*16];
            #pragma unroll
            for (int kk=0; kk<32; ++kk){
                float4 hv = *reinterpret_cast<const float4*>(&hs[kk*64 + b0]);
                float4 wv = *reinterpret_cast<const float4*>(&wl[kk*16 + c0]);
                acc[0][0]+=hv.x*wv.x; acc[0][1]+=hv.x*wv.y; acc[0][2]+=hv.x*wv.z; acc[0][3]+=hv.x*wv.w;
                acc[1][0]+=hv.y*wv.x; acc[1][1]+=hv.y*wv.y; acc[1][2]+=hv.y*wv.z; acc[1][3]+=hv.y*wv.w;
                acc[2][0]+=hv.z*wv.x; acc[2][1]+=hv.z*wv.y; acc[2][2]+=hv.z*wv.z; acc[2][3]+=hv.z*wv.w;
                acc[3][0]+=hv.w*wv.x; acc[3][1]+=hv.w*wv.y; acc[3][2]+=hv.w*wv.z; acc[3][3]+=hv.w*wv.w;
            }
            if (sc < 7){
                float* d = hstage[w][(sc+1)&1];
                #pragma unroll
                for (int it=0;it<8;++it)
                    *reinterpret_cast<float4*>(&d[it*256 + l*4]) = pre[it];
            }
        }
        #pragma unroll
        for (int bi=0;bi<4;++bi){
            float* pp = &pacc[w][(b0+bi)*17 + c0];
            pp[0]=acc[bi][0]; pp[1]=acc[bi][1]; pp[2]=acc[bi][2]; pp[3]=acc[bi][3];
        }
        __syncthreads();

        {   // phase C: one thread per (batch, h-col)
            float gs[4];
            #pragma unroll
            for (int g=0; g<4; ++g){
                const int idx = bq*17 + g*4 + hj;
                gs[g] = xwlds[idx] + pacc[0][idx] + pacc[1][idx] + pacc[2][idx] + pacc[3][idx];
            }
            float ig = 1.f/(1.f + __expf(-gs[0]));
            float fg = 1.f/(1.f + __expf(-gs[1]));
            float gg = tanhf(gs[2]);
            float og = 1.f/(1.f + __expf(-gs[3]));
            float c_new = fg * creg + ig * gg;
            float h_new = og * tanhf(c_new);
            creg = c_new;
            hout[bq*4 + hj] = h_new;
            if (last && t == NSTEPS-1){
                const int hcolg = bidx*4 + hj;
                hn[(size_t)bq*1024 + hcolg] = h_new;
                cn[(size_t)bq*1024 + hcolg] = c_new;
            }
        }
        __syncthreads();

        {   // publish h[t]: 128 x 64-bit returning swaps (ack == at L3)
            float* ringw = ring + (size_t)t*65536;
            if (tid < 128){
                const int coll = tid & 3;
                const int b0p  = (tid >> 2) << 1;
                float v0 = hout[b0p*4 + coll];
                float v1 = hout[(b0p+1)*4 + coll];
                unsigned long long pk =
                    ((unsigned long long)__float_as_uint(v1) << 32) | __float_as_uint(v0);
                unsigned long long old = __hip_atomic_exchange(
                    reinterpret_cast<unsigned long long*>(ringw + (bidx*4 + coll)*64 + b0p),
                    pk, __ATOMIC_RELAXED, __HIP_MEMORY_SCOPE_AGENT);
                asm volatile("" :: "v"(old));
            }
            if (tid < 64){
                float4 hv = *reinterpret_cast<const float4*>(&hout[tid*4]);
                *reinterpret_cast<float4*>(&out[(size_t)t*65536 + (size_t)tid*1024 + bidx*4]) = hv;
            }
        }
        gridbar(bar, t + 2);   // syncthreads inside drains the swaps first
    }
    ctg[bidx*256 + tid] = creg;
}

// ---------------------------------------------------------------------------
extern "C" void kernel_launch(void* const* d_in, const int* in_sizes, int n_in,
                              void* d_out, int out_size, void* d_ws, size_t ws_size,
                              hipStream_t stream)
{
    const float* x    = (const float*)d_in[0];
    const float* Wih0 = (const float*)d_in[1];
    const float* Whh0 = (const float*)d_in[2];
    const float* b0   = (const float*)d_in[3];
    const float* Wih1 = (const float*)d_in[4];
    const float* Whh1 = (const float*)d_in[5];
    const float* b1   = (const float*)d_in[6];

    float* out1 = (float*)d_out;
    float* hn   = out1 + (size_t)NROWS*HDIM;      // [2][64][1024]
    float* cn   = hn + 2*BATCH*HDIM;

    // layer-0 output scratch aliases out1 (safe: each out0 chunk is consumed
    // by the layer-1 GEMM before the layer-1 steps overwrite it).
    float* out0 = out1;

    char* wsb = (char*)d_ws;
    unsigned short* gp    = (unsigned short*)wsb;                      // 134,217,728 B
    unsigned short* WThi0 = (unsigned short*)(wsb + 134217728ull);     //   8,388,608
    unsigned short* WTlo0 = (unsigned short*)(wsb + 142606336ull);     //   8,388,608
    unsigned short* WThi1 = (unsigned short*)(wsb + 150994944ull);     //   8,388,608
    unsigned short* WTlo1 = (unsigned short*)(wsb + 159383552ull);     //   8,388,608
    float*          Whh0r = (float*)(wsb + 167772160ull);              //  16,777,216
    float*          Whh1r = (float*)(wsb + 184549376ull);              //  16,777,216
    float*          ring  = (float*)(wsb + 201326592ull);              //  67,371,008 (257 slots)
    float*          ctg   = (float*)(wsb + 268697600ull);              //     262,144
    unsigned int*   bar   = (unsigned int*)(wsb + 268959744ull);       //     262,144 (4 x 64KB)

    hipMemsetAsync(bar, 0, 262144, stream);
    split_transpose_w<<<dim3(128,32),256,0,stream>>>(Wih0, WThi0, WTlo0);
    split_transpose_w<<<dim3(128,32),256,0,stream>>>(Wih1, WThi1, WTlo1);
    reorder_whh<<<256,256,0,stream>>>(Whh0, Whh0r);
    reorder_whh<<<256,256,0,stream>>>(Whh1, Whh1r);

    const float*          Ain [2] = {x, out0};
    const unsigned short* Whi [2] = {WThi0, WThi1};
    const unsigned short* Wlo [2] = {WTlo0, WTlo1};
    const float*          bia [2] = {b0, b1};
    const float*          whr [2] = {Whh0r, Whh1r};
    float*                outp[2] = {out0, out1};

    for (int layer=0; layer<2; ++layer){
        float* hnL = hn + (size_t)layer*BATCH*HDIM;
        float* cnL = cn + (size_t)layer*BATCH*HDIM;
        for (int chunk=0; chunk<2; ++chunk){
            gemm_xw_split<<<4096,256,0,stream>>>(
                Ain[layer] + (size_t)chunk*NSTEPS*BATCH*HDIM,
                Whi[layer], Wlo[layer], bia[layer], gp);

            const unsigned short* gpc = gp;
            const float* wh = whr[layer];
            float* op = outp[layer] + (size_t)chunk*NSTEPS*BATCH*HDIM;
            float* rg = ring; float* cg_ = ctg;
            unsigned int* br = bar + (size_t)(layer*2 + chunk)*16384;
            int first = (chunk == 0), last = (chunk == 1);
            void* args[10] = {(void*)&gpc, (void*)&wh, (void*)&op, (void*)&rg,
                              (void*)&cg_, (void*)&hnL, (void*)&cnL,
                              (void*)&br, (void*)&first, (void*)&last};
            hipLaunchCooperativeKernel(reinterpret_cast<void*>(&lstm_ring),
                                       dim3(256), dim3(256), args, 0, stream);
        }
    }
}

// Round 13
// 18111.998 us; speedup vs baseline: 2.2767x; 1.9485x over previous
//
#include <hip/hip_runtime.h>
#include <hip/hip_bf16.h>

#define TSTEPS 512
#define NSTEPS 256          // steps per chunk
#define BATCH  64
#define HDIM   1024
#define NROWS  (TSTEPS*BATCH)   // 32768

typedef __attribute__((ext_vector_type(8))) short bf16x8;
typedef __attribute__((ext_vector_type(4))) float f32x4;

__device__ __forceinline__ unsigned short f2bf(float f){
    unsigned u = __float_as_uint(f);
    u += 0x7fffu + ((u >> 16) & 1u);
    return (unsigned short)(u >> 16);
}
__device__ __forceinline__ float bf2f(unsigned short s){
    return __uint_as_float(((unsigned)s) << 16);
}

// ---------------------------------------------------------------------------
// Contention-free broadcast grid barrier over 512 VIRTUAL blocks hosted in
// 256 real blocks of 512 threads (r11 discipline: private 128B lines).
//   arrival slots: region[v*32]           v=2..511
//   release words: region[16384 + v*32]   v=2..511
// Block 0 (vbids 0,1) is the collector: 512 threads poll one slot each,
// then release 512 private words. Workers: tid 0 / tid 256 arrive + poll
// their own rel line. h coherence: returning atomic swaps (ack == at L3) +
// fresh-address reads; __syncthreads drains each wave's vmcnt before arrival.
// ---------------------------------------------------------------------------
__device__ __forceinline__ void gridbar2(unsigned int* region, unsigned int epoch){
    unsigned int* slots = region;
    unsigned int* rel   = region + 16384;
    __syncthreads();    // all waves' vmem (incl. h swaps) acked at L3
    if (blockIdx.x == 0){
        const int i = threadIdx.x;             // 0..511
        if (i >= 2){                           // vbids 2..511 (worker blocks)
            while (__hip_atomic_load(&slots[i*32], __ATOMIC_RELAXED, __HIP_MEMORY_SCOPE_AGENT) < epoch)
                __builtin_amdgcn_s_sleep(2);
        }
        __syncthreads();
        {   // broadcast: 512 private release words (parallel returning swaps)
            unsigned int old = __hip_atomic_exchange(&rel[i*32], epoch,
                                   __ATOMIC_RELAXED, __HIP_MEMORY_SCOPE_AGENT);
            asm volatile("" :: "v"(old));
        }
    } else {
        const int v0 = blockIdx.x*2;
        if (threadIdx.x == 0){
            unsigned int old = __hip_atomic_exchange(&slots[v0*32], epoch,
                                   __ATOMIC_RELAXED, __HIP_MEMORY_SCOPE_AGENT);
            asm volatile("" :: "v"(old));
            while (__hip_atomic_load(&rel[v0*32], __ATOMIC_RELAXED, __HIP_MEMORY_SCOPE_AGENT) < epoch)
                __builtin_amdgcn_s_sleep(2);
        }
        if (threadIdx.x == 256){
            unsigned int old = __hip_atomic_exchange(&slots[(v0+1)*32], epoch,
                                   __ATOMIC_RELAXED, __HIP_MEMORY_SCOPE_AGENT);
            asm volatile("" :: "v"(old));
            while (__hip_atomic_load(&rel[(v0+1)*32], __ATOMIC_RELAXED, __HIP_MEMORY_SCOPE_AGENT) < epoch)
                __builtin_amdgcn_s_sleep(2);
        }
        __syncthreads();
    }
    asm volatile("" ::: "memory");  // no hoisting ring loads above
}

// ---------------------------------------------------------------------------
// W [1024][4096] fp32 -> WThi/WTlo [4096][1024] bf16 (transpose + split)
// ---------------------------------------------------------------------------
__global__ __launch_bounds__(256)
void split_transpose_w(const float* __restrict__ W,
                       unsigned short* __restrict__ WThi,
                       unsigned short* __restrict__ WTlo)
{
    __shared__ float tile[32][33];
    const int c0 = blockIdx.x * 32;
    const int k0 = blockIdx.y * 32;
    const int tx = threadIdx.x & 31, ty = threadIdx.x >> 5;
    #pragma unroll
    for (int r=0;r<4;++r)
        tile[ty + r*8][tx] = W[(size_t)(k0 + ty + r*8)*4096 + c0 + tx];
    __syncthreads();
    #pragma unroll
    for (int r=0;r<4;++r){
        float v = tile[tx][ty + r*8];
        unsigned short hi = f2bf(v);
        unsigned short lo = f2bf(v - bf2f(hi));
        WThi[(size_t)(c0 + ty + r*8)*1024 + k0 + tx] = hi;
        WTlo[(size_t)(c0 + ty + r*8)*1024 + k0 + tx] = lo;
    }
}

// ---------------------------------------------------------------------------
// W_hh [1024][4096] fp32 -> WhhR [512][1024][8] fp32, vblock-contiguous:
//   WhhR[vb][k][j] = Whh[k][(j>>1)*1024 + vb*2 + (j&1)]
// ---------------------------------------------------------------------------
__global__ __launch_bounds__(256)
void reorder_whh2(const float* __restrict__ W, float* __restrict__ Wr)
{
    const int bid = blockIdx.x;          // 0..511
    const int tid = threadIdx.x;
    for (int k = tid; k < 1024; k += 256){
        float* dst = Wr + ((size_t)bid*1024 + k)*8;
        #pragma unroll
        for (int j=0;j<8;++j)
            dst[j] = W[(size_t)k*4096 + (j>>1)*1024 + bid*2 + (j&1)];
    }
}

// ---------------------------------------------------------------------------
// Split-bf16 MFMA GEMM over one 16384-row chunk (proven structure, bf16 out),
// epilogue writes 8-j gates layout:
//   gp[t][vb512][b][8],  j = g*2 + hj,  col = g*1024 + vb*2 + hj
// ---------------------------------------------------------------------------
__global__ __launch_bounds__(256)
void gemm_xw_split(const float* __restrict__ A,
                   const unsigned short* __restrict__ BThi,
                   const unsigned short* __restrict__ BTlo,
                   const float* __restrict__ bias, unsigned short* __restrict__ gp)
{
    __shared__ __align__(16) unsigned short Ahi[128*32];
    __shared__ __align__(16) unsigned short Alo[128*32];
    __shared__ __align__(16) unsigned short Bhi[128*32];
    __shared__ __align__(16) unsigned short Blo[128*32];

    const int tid = threadIdx.x;
    const int w = tid >> 6, l = tid & 63;
    const int bx = blockIdx.x & 31, by = blockIdx.x >> 5;
    const int row0 = by*128, col0 = bx*128;
    const int wrow = (w>>1)*64, wcol = (w&1)*64;

    const int srow  = l >> 2;
    const int skoff = (l & 3) * 8;

    const int arow  = tid >> 1;
    const int akoff = (tid & 1) * 16;
    const float* aptr = A + (size_t)(row0 + arow)*1024 + akoff;

    f32x4 acc[4][4];
    #pragma unroll
    for (int m=0;m<4;++m)
        #pragma unroll
        for (int n=0;n<4;++n)
            acc[m][n] = (f32x4){0.f,0.f,0.f,0.f};

    for (int k0=0; k0<1024; k0+=32){
        #pragma unroll
        for (int c=0;c<2;++c){
            const int i = w*2 + c;
            const unsigned short* gh = BThi + (size_t)(col0 + i*16 + srow)*1024 + k0 + skoff;
            const unsigned short* gl = BTlo + (size_t)(col0 + i*16 + srow)*1024 + k0 + skoff;
            __builtin_amdgcn_global_load_lds((const __attribute__((address_space(1))) void*)gh,
                (__attribute__((address_space(3))) void*)(Bhi + i*512), 16, 0, 0);
            __builtin_amdgcn_global_load_lds((const __attribute__((address_space(1))) void*)gl,
                (__attribute__((address_space(3))) void*)(Blo + i*512), 16, 0, 0);
        }
        {
            float4 x0 = *reinterpret_cast<const float4*>(aptr + k0);
            float4 x1 = *reinterpret_cast<const float4*>(aptr + k0 + 4);
            float4 x2 = *reinterpret_cast<const float4*>(aptr + k0 + 8);
            float4 x3 = *reinterpret_cast<const float4*>(aptr + k0 + 12);
            float xs[16] = {x0.x,x0.y,x0.z,x0.w, x1.x,x1.y,x1.z,x1.w,
                            x2.x,x2.y,x2.z,x2.w, x3.x,x3.y,x3.z,x3.w};
            unsigned short hs[16], ls[16];
            #pragma unroll
            for (int e=0;e<16;++e){
                hs[e] = f2bf(xs[e]);
                ls[e] = f2bf(xs[e] - bf2f(hs[e]));
            }
            #pragma unroll
            for (int q=0;q<4;++q){
                ushort4 h4; h4.x=hs[q*4]; h4.y=hs[q*4+1]; h4.z=hs[q*4+2]; h4.w=hs[q*4+3];
                ushort4 l4; l4.x=ls[q*4]; l4.y=ls[q*4+1]; l4.z=ls[q*4+2]; l4.w=ls[q*4+3];
                *reinterpret_cast<ushort4*>(&Ahi[arow*32 + akoff + q*4]) = h4;
                *reinterpret_cast<ushort4*>(&Alo[arow*32 + akoff + q*4]) = l4;
            }
        }
        __syncthreads();
        bf16x8 afh[4], afl[4], bfh[4], bfl[4];
        #pragma unroll
        for (int m=0;m<4;++m){
            const int off = (wrow + m*16 + (l&15))*32 + (l>>4)*8;
            afh[m] = *reinterpret_cast<const bf16x8*>(&Ahi[off]);
            afl[m] = *reinterpret_cast<const bf16x8*>(&Alo[off]);
        }
        #pragma unroll
        for (int n=0;n<4;++n){
            const int off = (wcol + n*16 + (l&15))*32 + (l>>4)*8;
            bfh[n] = *reinterpret_cast<const bf16x8*>(&Bhi[off]);
            bfl[n] = *reinterpret_cast<const bf16x8*>(&Blo[off]);
        }
        #pragma unroll
        for (int m=0;m<4;++m)
            #pragma unroll
            for (int n=0;n<4;++n){
                acc[m][n] = __builtin_amdgcn_mfma_f32_16x16x32_bf16(afh[m], bfh[n], acc[m][n], 0,0,0);
                acc[m][n] = __builtin_amdgcn_mfma_f32_16x16x32_bf16(afl[m], bfh[n], acc[m][n], 0,0,0);
                acc[m][n] = __builtin_amdgcn_mfma_f32_16x16x32_bf16(afh[m], bfl[n], acc[m][n], 0,0,0);
            }
        __syncthreads();
    }

    #pragma unroll
    for (int n=0;n<4;++n){
        const int n_g = col0 + wcol + n*16 + (l&15);
        const float bv = bias[n_g];
        const int g = n_g >> 10, hcol = n_g & 1023;
        const int vb = hcol >> 1, hj = hcol & 1;
        #pragma unroll
        for (int m=0;m<4;++m){
            #pragma unroll
            for (int r=0;r<4;++r){
                const int m_g = row0 + wrow + m*16 + (l>>4)*4 + r;
                const int t = m_g >> 6, b = m_g & 63;
                gp[(((size_t)t*512 + vb)*64 + b)*8 + g*2 + hj] = f2bf(acc[m][n][r] + bv);
            }
        }
    }
}

// ---------------------------------------------------------------------------
// Persistent recurrence: 256 real blocks x 512 threads; each real block hosts
// TWO virtual blocks (vb = tid>>8), each owning h-cols {vbid*2, vbid*2+1}.
// 8 waves/CU for latency hiding. fp32 arithmetic, r12 per-vblock logic.
// h exchanged through the 257-slot ring: write via returning 64-bit swaps,
// read via plain loads at fresh addresses. c-state in register.
// ---------------------------------------------------------------------------
__global__ __launch_bounds__(512)
void lstm_ring2(const unsigned short* __restrict__ gp, const float* __restrict__ WhhR,
                float* __restrict__ out, float* __restrict__ ring,
                float* __restrict__ ctg, float* __restrict__ hn, float* __restrict__ cn,
                unsigned int* __restrict__ bar, int first, int last)
{
    __shared__ float Wlds[2][1024*8];        // 64 KB  [vb][k][j]
    __shared__ float hstage[2][4][2][1024];  // 64 KB  per-vb per-wave dbuf [16k][64b]
    __shared__ float pacc[2][4][64*9];       // 18 KB  padded [vb][w][b][j]
    __shared__ float xwlds[2][64*9];         //  4.5KB padded [vb][b][j]
    __shared__ float hout[2][128];           //  1 KB  [vb][b*2+hj]

    const int tid  = threadIdx.x;
    const int vb   = tid >> 8;               // virtual block half
    const int vt   = tid & 255;
    const int vbid = blockIdx.x*2 + vb;      // 0..511
    const int w = vt >> 6, l = vt & 63;

    {   // stage W_hh slice (32 KB per vblock): 8 x global_load_lds(16B)
        const float* base = WhhR + (size_t)vbid*8192;
        #pragma unroll
        for (int i=0;i<8;++i){
            const float* s = base + i*1024 + w*256 + l*4;
            __builtin_amdgcn_global_load_lds((const __attribute__((address_space(1))) void*)s,
                (__attribute__((address_space(3))) void*)(&Wlds[vb][i*1024 + w*256]), 16, 0, 0);
        }
    }
    float creg = 0.f;
    if (!first && vt < 128) creg = ctg[vbid*128 + vt];
    if (first && vt < 128){   // zero slot 256 (h_{-1}) for our 2 columns
        unsigned int old = __hip_atomic_exchange(
            (unsigned int*)(ring + (size_t)256*65536 + (vbid*2 + (vt>>6))*64 + (vt&63)),
            0u, __ATOMIC_RELAXED, __HIP_MEMORY_SCOPE_AGENT);
        asm volatile("" :: "v"(old));
    }
    gridbar2(bar, 1);   // zero-slot at L3 + W LDS staged

    const int c0 = (l & 1) << 2;         // 4 gate-cols per lane
    const int b0 = (l >> 1) << 1;        // 2 batches per lane
    const int kbase = w << 8;            // wave K-range [kbase, kbase+256)
    const int bq = vt & 63;
    const int hj = vt >> 6;              // phase-C col (vt<128)

    for (int t=0; t<NSTEPS; ++t){
        if (vt < 128){   // xW[t] slice (bf16, 512 elems) -> xwlds padded [b][j]
            ushort4 v = *reinterpret_cast<const ushort4*>(gp + ((size_t)t*512 + vbid)*512 + vt*4);
            const int b = vt >> 1, j0 = (vt & 1)*4;
            float* xp = &xwlds[vb][b*9 + j0];
            xp[0]=bf2f(v.x); xp[1]=bf2f(v.y); xp[2]=bf2f(v.z); xp[3]=bf2f(v.w);
        }

        const int rs = (t > 0) ? (t-1) : (first ? 256 : NSTEPS-1);
        const float* hc = ring + (size_t)rs*65536 + (size_t)kbase*64;
        float4 pre[4];
        #pragma unroll
        for (int it=0;it<4;++it)
            pre[it] = *reinterpret_cast<const float4*>(hc + it*256 + l*4);
        #pragma unroll
        for (int it=0;it<4;++it)
            *reinterpret_cast<float4*>(&hstage[vb][w][0][it*256 + l*4]) = pre[it];

        float acc[2][4];
        #pragma unroll
        for (int i2=0;i2<2;++i2){acc[i2][0]=0.f;acc[i2][1]=0.f;acc[i2][2]=0.f;acc[i2][3]=0.f;}

        for (int sc=0; sc<16; ++sc){
            if (sc < 15){
                const float* s2 = hc + (size_t)(sc+1)*1024;
                #pragma unroll
                for (int it=0;it<4;++it)
                    pre[it] = *reinterpret_cast<const float4*>(s2 + it*256 + l*4);
            }
            const float* hs = hstage[vb][w][sc&1];
            const float* wl = &Wlds[vb][(size_t)(kbase + sc*16)*8];
            #pragma unroll
            for (int kk=0; kk<16; ++kk){
                float2 hv = *reinterpret_cast<const float2*>(&hs[kk*64 + b0]);
                float4 wv = *reinterpret_cast<const float4*>(&wl[kk*8 + c0]);
                acc[0][0]+=hv.x*wv.x; acc[0][1]+=hv.x*wv.y; acc[0][2]+=hv.x*wv.z; acc[0][3]+=hv.x*wv.w;
                acc[1][0]+=hv.y*wv.x; acc[1][1]+=hv.y*wv.y; acc[1][2]+=hv.y*wv.z; acc[1][3]+=hv.y*wv.w;
            }
            if (sc < 15){
                float* d = hstage[vb][w][(sc+1)&1];
                #pragma unroll
                for (int it=0;it<4;++it)
                    *reinterpret_cast<float4*>(&d[it*256 + l*4]) = pre[it];
            }
        }
        #pragma unroll
        for (int bi=0;bi<2;++bi)
            *reinterpret_cast<float4*>(&pacc[vb][w][(b0+bi)*9 + c0]) =
                make_float4(acc[bi][0],acc[bi][1],acc[bi][2],acc[bi][3]);
        __syncthreads();

        if (vt < 128){   // phase C: one thread per (batch, h-col)
            float gs[4];
            #pragma unroll
            for (int g=0; g<4; ++g){
                const int idx = bq*9 + g*2 + hj;
                gs[g] = xwlds[vb][idx] + pacc[vb][0][idx] + pacc[vb][1][idx]
                        + pacc[vb][2][idx] + pacc[vb][3][idx];
            }
            float ig = 1.f/(1.f + __expf(-gs[0]));
            float fg = 1.f/(1.f + __expf(-gs[1]));
            float gg = tanhf(gs[2]);
            float og = 1.f/(1.f + __expf(-gs[3]));
            float c_new = fg * creg + ig * gg;
            float h_new = og * tanhf(c_new);
            creg = c_new;
            hout[vb][bq*2 + hj] = h_new;
            if (last && t == NSTEPS-1){
                const int hcolg = vbid*2 + hj;
                hn[(size_t)bq*1024 + hcolg] = h_new;
                cn[(size_t)bq*1024 + hcolg] = c_new;
            }
        }
        __syncthreads();

        if (vt < 64){   // publish h[t] (64-bit returning swaps) + out write
            const int col = vt >> 5, bp = (vt & 31) << 1;
            float v0 = hout[vb][bp*2 + col];
            float v1 = hout[vb][(bp+1)*2 + col];
            unsigned long long pk =
                ((unsigned long long)__float_as_uint(v1) << 32) | __float_as_uint(v0);
            unsigned long long old = __hip_atomic_exchange(
                reinterpret_cast<unsigned long long*>(
                    ring + (size_t)t*65536 + (vbid*2 + col)*64 + bp),
                pk, __ATOMIC_RELAXED, __HIP_MEMORY_SCOPE_AGENT);
            asm volatile("" :: "v"(old));
            float2 ho; ho.x = hout[vb][vt*2]; ho.y = hout[vb][vt*2+1];
            *reinterpret_cast<float2*>(&out[(size_t)t*65536 + (size_t)vt*1024 + vbid*2]) = ho;
        }
        gridbar2(bar, t + 2);   // syncthreads inside drains the swaps first
    }
    if (vt < 128) ctg[vbid*128 + vt] = creg;
}

// ---------------------------------------------------------------------------
extern "C" void kernel_launch(void* const* d_in, const int* in_sizes, int n_in,
                              void* d_out, int out_size, void* d_ws, size_t ws_size,
                              hipStream_t stream)
{
    const float* x    = (const float*)d_in[0];
    const float* Wih0 = (const float*)d_in[1];
    const float* Whh0 = (const float*)d_in[2];
    const float* b0   = (const float*)d_in[3];
    const float* Wih1 = (const float*)d_in[4];
    const float* Whh1 = (const float*)d_in[5];
    const float* b1   = (const float*)d_in[6];

    float* out1 = (float*)d_out;
    float* hn   = out1 + (size_t)NROWS*HDIM;      // [2][64][1024]
    float* cn   = hn + 2*BATCH*HDIM;

    // layer-0 output scratch aliases out1 (safe: each out0 chunk is consumed
    // by the layer-1 GEMM before the layer-1 steps overwrite it).
    float* out0 = out1;

    char* wsb = (char*)d_ws;
    unsigned short* gp    = (unsigned short*)wsb;                      // 134,217,728 B
    unsigned short* WThi0 = (unsigned short*)(wsb + 134217728ull);     //   8,388,608
    unsigned short* WTlo0 = (unsigned short*)(wsb + 142606336ull);     //   8,388,608
    unsigned short* WThi1 = (unsigned short*)(wsb + 150994944ull);     //   8,388,608
    unsigned short* WTlo1 = (unsigned short*)(wsb + 159383552ull);     //   8,388,608
    float*          Whh0r = (float*)(wsb + 167772160ull);              //  16,777,216
    float*          Whh1r = (float*)(wsb + 184549376ull);              //  16,777,216
    float*          ring  = (float*)(wsb + 201326592ull);              //  67,371,008 (257 slots)
    float*          ctg   = (float*)(wsb + 268697600ull);              //     262,144
    unsigned int*   bar   = (unsigned int*)(wsb + 268959744ull);       //     524,288 (4 x 128KB)

    hipMemsetAsync(bar, 0, 524288, stream);
    split_transpose_w<<<dim3(128,32),256,0,stream>>>(Wih0, WThi0, WTlo0);
    split_transpose_w<<<dim3(128,32),256,0,stream>>>(Wih1, WThi1, WTlo1);
    reorder_whh2<<<512,256,0,stream>>>(Whh0, Whh0r);
    reorder_whh2<<<512,256,0,stream>>>(Whh1, Whh1r);

    const float*          Ain [2] = {x, out0};
    const unsigned short* Whi [2] = {WThi0, WThi1};
    const unsigned short* Wlo [2] = {WTlo0, WTlo1};
    const float*          bia [2] = {b0, b1};
    const float*          whr [2] = {Whh0r, Whh1r};
    float*                outp[2] = {out0, out1};

    for (int layer=0; layer<2; ++layer){
        float* hnL = hn + (size_t)layer*BATCH*HDIM;
        float* cnL = cn + (size_t)layer*BATCH*HDIM;
        for (int chunk=0; chunk<2; ++chunk){
            gemm_xw_split<<<4096,256,0,stream>>>(
                Ain[layer] + (size_t)chunk*NSTEPS*BATCH*HDIM,
                Whi[layer], Wlo[layer], bia[layer], gp);

            const unsigned short* gpc = gp;
            const float* wh = whr[layer];
            float* op = outp[layer] + (size_t)chunk*NSTEPS*BATCH*HDIM;
            float* rg = ring; float* cg_ = ctg;
            unsigned int* br = bar + (size_t)(layer*2 + chunk)*32768;
            int first = (chunk == 0), last = (chunk == 1);
            void* args[10] = {(void*)&gpc, (void*)&wh, (void*)&op, (void*)&rg,
                              (void*)&cg_, (void*)&hnL, (void*)&cnL,
                              (void*)&br, (void*)&first, (void*)&last};
            hipLaunchCooperativeKernel(reinterpret_cast<void*>(&lstm_ring2),
                                       dim3(256), dim3(512), args, 0, stream);
        }
    }
}

// Round 14
// 17075.635 us; speedup vs baseline: 2.4149x; 1.0607x over previous
//
#include <hip/hip_runtime.h>
#include <hip/hip_bf16.h>

#define TSTEPS 512
#define NSTEPS 256          // steps per chunk
#define BATCH  64
#define HDIM   1024
#define NROWS  (TSTEPS*BATCH)   // 32768

typedef __attribute__((ext_vector_type(8))) short bf16x8;
typedef __attribute__((ext_vector_type(4))) float f32x4;

__device__ __forceinline__ unsigned short f2bf(float f){
    unsigned u = __float_as_uint(f);
    u += 0x7fffu + ((u >> 16) & 1u);
    return (unsigned short)(u >> 16);
}
__device__ __forceinline__ float bf2f(unsigned short s){
    return __uint_as_float(((unsigned)s) << 16);
}

// ---------------------------------------------------------------------------
// Contention-free broadcast grid barrier, 256 real blocks (r11-proven
// topology), adapted to 1024-thread blocks (only threads <256 of block 0
// poll/release). Private 128B lines:
//   arrival slots: region[b*32]          b=0..255
//   release words: region[8192 + b*32]   b=0..255
// h coherence: returning atomic swaps (ack == at L3) + fresh-address reads;
// __syncthreads drains each wave's vmcnt before arrival.
// ---------------------------------------------------------------------------
__device__ __forceinline__ void gridbar(unsigned int* region, unsigned int epoch){
    unsigned int* slots = region;
    unsigned int* rel   = region + 8192;
    __syncthreads();    // all waves' vmem (incl. h swaps) acked at L3
    if (blockIdx.x == 0){
        const int i = threadIdx.x;
        if (i > 0 && i < 256){
            while (__hip_atomic_load(&slots[i*32], __ATOMIC_RELAXED, __HIP_MEMORY_SCOPE_AGENT) < epoch)
                __builtin_amdgcn_s_sleep(2);
        }
        __syncthreads();
        if (i < 256){
            unsigned int old = __hip_atomic_exchange(&rel[i*32], epoch,
                                   __ATOMIC_RELAXED, __HIP_MEMORY_SCOPE_AGENT);
            asm volatile("" :: "v"(old));
        }
    } else {
        if (threadIdx.x == 0){
            unsigned int old = __hip_atomic_exchange(&slots[blockIdx.x*32], epoch,
                                   __ATOMIC_RELAXED, __HIP_MEMORY_SCOPE_AGENT);
            asm volatile("" :: "v"(old));   // returning form (ack == visible)
            while (__hip_atomic_load(&rel[blockIdx.x*32], __ATOMIC_RELAXED, __HIP_MEMORY_SCOPE_AGENT) < epoch)
                __builtin_amdgcn_s_sleep(2);
        }
        __syncthreads();
    }
    asm volatile("" ::: "memory");  // no hoisting ring loads above
}

// ---------------------------------------------------------------------------
// W [1024][4096] fp32 -> WThi/WTlo [4096][1024] bf16 (transpose + split)
// ---------------------------------------------------------------------------
__global__ __launch_bounds__(256)
void split_transpose_w(const float* __restrict__ W,
                       unsigned short* __restrict__ WThi,
                       unsigned short* __restrict__ WTlo)
{
    __shared__ float tile[32][33];
    const int c0 = blockIdx.x * 32;
    const int k0 = blockIdx.y * 32;
    const int tx = threadIdx.x & 31, ty = threadIdx.x >> 5;
    #pragma unroll
    for (int r=0;r<4;++r)
        tile[ty + r*8][tx] = W[(size_t)(k0 + ty + r*8)*4096 + c0 + tx];
    __syncthreads();
    #pragma unroll
    for (int r=0;r<4;++r){
        float v = tile[tx][ty + r*8];
        unsigned short hi = f2bf(v);
        unsigned short lo = f2bf(v - bf2f(hi));
        WThi[(size_t)(c0 + ty + r*8)*1024 + k0 + tx] = hi;
        WTlo[(size_t)(c0 + ty + r*8)*1024 + k0 + tx] = lo;
    }
}

// ---------------------------------------------------------------------------
// W_hh [1024][4096] fp32 -> WhhR [512][1024][8] fp32, vblock-contiguous:
//   WhhR[vb][k][j] = Whh[k][(j>>1)*1024 + vb*2 + (j&1)]
// ---------------------------------------------------------------------------
__global__ __launch_bounds__(256)
void reorder_whh2(const float* __restrict__ W, float* __restrict__ Wr)
{
    const int bid = blockIdx.x;          // 0..511
    const int tid = threadIdx.x;
    for (int k = tid; k < 1024; k += 256){
        float* dst = Wr + ((size_t)bid*1024 + k)*8;
        #pragma unroll
        for (int j=0;j<8;++j)
            dst[j] = W[(size_t)k*4096 + (j>>1)*1024 + bid*2 + (j&1)];
    }
}

// ---------------------------------------------------------------------------
// Split-bf16 MFMA GEMM over one 16384-row chunk (proven structure, bf16 out),
// epilogue writes 8-j gates layout:
//   gp[t][vb512][b][8],  j = g*2 + hj,  col = g*1024 + vb*2 + hj
// ---------------------------------------------------------------------------
__global__ __launch_bounds__(256)
void gemm_xw_split(const float* __restrict__ A,
                   const unsigned short* __restrict__ BThi,
                   const unsigned short* __restrict__ BTlo,
                   const float* __restrict__ bias, unsigned short* __restrict__ gp)
{
    __shared__ __align__(16) unsigned short Ahi[128*32];
    __shared__ __align__(16) unsigned short Alo[128*32];
    __shared__ __align__(16) unsigned short Bhi[128*32];
    __shared__ __align__(16) unsigned short Blo[128*32];

    const int tid = threadIdx.x;
    const int w = tid >> 6, l = tid & 63;
    const int bx = blockIdx.x & 31, by = blockIdx.x >> 5;
    const int row0 = by*128, col0 = bx*128;
    const int wrow = (w>>1)*64, wcol = (w&1)*64;

    const int srow  = l >> 2;
    const int skoff = (l & 3) * 8;

    const int arow  = tid >> 1;
    const int akoff = (tid & 1) * 16;
    const float* aptr = A + (size_t)(row0 + arow)*1024 + akoff;

    f32x4 acc[4][4];
    #pragma unroll
    for (int m=0;m<4;++m)
        #pragma unroll
        for (int n=0;n<4;++n)
            acc[m][n] = (f32x4){0.f,0.f,0.f,0.f};

    for (int k0=0; k0<1024; k0+=32){
        #pragma unroll
        for (int c=0;c<2;++c){
            const int i = w*2 + c;
            const unsigned short* gh = BThi + (size_t)(col0 + i*16 + srow)*1024 + k0 + skoff;
            const unsigned short* gl = BTlo + (size_t)(col0 + i*16 + srow)*1024 + k0 + skoff;
            __builtin_amdgcn_global_load_lds((const __attribute__((address_space(1))) void*)gh,
                (__attribute__((address_space(3))) void*)(Bhi + i*512), 16, 0, 0);
            __builtin_amdgcn_global_load_lds((const __attribute__((address_space(1))) void*)gl,
                (__attribute__((address_space(3))) void*)(Blo + i*512), 16, 0, 0);
        }
        {
            float4 x0 = *reinterpret_cast<const float4*>(aptr + k0);
            float4 x1 = *reinterpret_cast<const float4*>(aptr + k0 + 4);
            float4 x2 = *reinterpret_cast<const float4*>(aptr + k0 + 8);
            float4 x3 = *reinterpret_cast<const float4*>(aptr + k0 + 12);
            float xs[16] = {x0.x,x0.y,x0.z,x0.w, x1.x,x1.y,x1.z,x1.w,
                            x2.x,x2.y,x2.z,x2.w, x3.x,x3.y,x3.z,x3.w};
            unsigned short hs[16], ls[16];
            #pragma unroll
            for (int e=0;e<16;++e){
                hs[e] = f2bf(xs[e]);
                ls[e] = f2bf(xs[e] - bf2f(hs[e]));
            }
            #pragma unroll
            for (int q=0;q<4;++q){
                ushort4 h4; h4.x=hs[q*4]; h4.y=hs[q*4+1]; h4.z=hs[q*4+2]; h4.w=hs[q*4+3];
                ushort4 l4; l4.x=ls[q*4]; l4.y=ls[q*4+1]; l4.z=ls[q*4+2]; l4.w=ls[q*4+3];
                *reinterpret_cast<ushort4*>(&Ahi[arow*32 + akoff + q*4]) = h4;
                *reinterpret_cast<ushort4*>(&Alo[arow*32 + akoff + q*4]) = l4;
            }
        }
        __syncthreads();
        bf16x8 afh[4], afl[4], bfh[4], bfl[4];
        #pragma unroll
        for (int m=0;m<4;++m){
            const int off = (wrow + m*16 + (l&15))*32 + (l>>4)*8;
            afh[m] = *reinterpret_cast<const bf16x8*>(&Ahi[off]);
            afl[m] = *reinterpret_cast<const bf16x8*>(&Alo[off]);
        }
        #pragma unroll
        for (int n=0;n<4;++n){
            const int off = (wcol + n*16 + (l&15))*32 + (l>>4)*8;
            bfh[n] = *reinterpret_cast<const bf16x8*>(&Bhi[off]);
            bfl[n] = *reinterpret_cast<const bf16x8*>(&Blo[off]);
        }
        #pragma unroll
        for (int m=0;m<4;++m)
            #pragma unroll
            for (int n=0;n<4;++n){
                acc[m][n] = __builtin_amdgcn_mfma_f32_16x16x32_bf16(afh[m], bfh[n], acc[m][n], 0,0,0);
                acc[m][n] = __builtin_amdgcn_mfma_f32_16x16x32_bf16(afl[m], bfh[n], acc[m][n], 0,0,0);
                acc[m][n] = __builtin_amdgcn_mfma_f32_16x16x32_bf16(afh[m], bfl[n], acc[m][n], 0,0,0);
            }
        __syncthreads();
    }

    #pragma unroll
    for (int n=0;n<4;++n){
        const int n_g = col0 + wcol + n*16 + (l&15);
        const float bv = bias[n_g];
        const int g = n_g >> 10, hcol = n_g & 1023;
        const int vb = hcol >> 1, hj = hcol & 1;
        #pragma unroll
        for (int m=0;m<4;++m){
            #pragma unroll
            for (int r=0;r<4;++r){
                const int m_g = row0 + wrow + m*16 + (l>>4)*4 + r;
                const int t = m_g >> 6, b = m_g & 63;
                gp[(((size_t)t*512 + vb)*64 + b)*8 + g*2 + hj] = f2bf(acc[m][n][r] + bv);
            }
        }
    }
}

// ---------------------------------------------------------------------------
// Persistent recurrence: 256 real blocks x 1024 threads = 16 waves/CU.
// Each real block hosts TWO vblocks (vb = tid>>9) of 512 threads; each vblock
// owns h-cols {vbid*2, vbid*2+1} with 8 waves (K-range 128/wave).
// W_hh slice in LDS; h through the 257-slot ring (returning 64-bit swaps to
// write, plain fresh-address loads to read). c-state in register.
// ---------------------------------------------------------------------------
__global__ __launch_bounds__(1024, 4)
void lstm_ring3(const unsigned short* __restrict__ gp, const float* __restrict__ WhhR,
                float* __restrict__ out, float* __restrict__ ring,
                float* __restrict__ ctg, float* __restrict__ hn, float* __restrict__ cn,
                unsigned int* __restrict__ bar, int first, int last)
{
    __shared__ float Wlds[2][1024*8];        // 64 KB   [vb][k][j]
    __shared__ float hstage[2][8][2][256];   // 32 KB   [vb][wave][dbuf][4k x 64b]
    __shared__ float pacc[2][8][64*9];       // 36.9 KB padded [vb][wave][b][j]
    __shared__ float xwlds[2][64*9];         //  4.6 KB padded [vb][b][j]
    __shared__ float hout[2][128];           //  1 KB   [vb][b*2+hj]

    const int tid  = threadIdx.x;
    const int vb   = tid >> 9;               // virtual block half
    const int vt   = tid & 511;
    const int vbid = blockIdx.x*2 + vb;      // 0..511
    const int w8 = vt >> 6, l = vt & 63;     // 8 waves per vblock

    {   // stage W_hh slice (32 KB per vblock): 4 passes x global_load_lds(16B)
        const float* base = WhhR + (size_t)vbid*8192;
        #pragma unroll
        for (int i=0;i<4;++i){
            const float* s = base + i*2048 + w8*256 + l*4;
            __builtin_amdgcn_global_load_lds((const __attribute__((address_space(1))) void*)s,
                (__attribute__((address_space(3))) void*)(&Wlds[vb][i*2048 + w8*256]), 16, 0, 0);
        }
    }
    float creg = 0.f;
    if (!first && vt < 128) creg = ctg[vbid*128 + vt];
    if (first && vt < 128){   // zero slot 256 (h_{-1}) for our 2 columns
        unsigned int old = __hip_atomic_exchange(
            (unsigned int*)(ring + (size_t)256*65536 + (vbid*2 + (vt>>6))*64 + (vt&63)),
            0u, __ATOMIC_RELAXED, __HIP_MEMORY_SCOPE_AGENT);
        asm volatile("" :: "v"(old));
    }
    gridbar(bar, 1);   // zero-slot at L3 + W LDS staged

    const int c0 = (l & 1) << 2;         // 4 gate-cols per lane
    const int b0 = (l >> 1) << 1;        // 2 batches per lane
    const int kbase = w8 << 7;           // wave K-range [kbase, kbase+128)
    const int bq = vt & 63;
    const int hj = vt >> 6;              // phase-C col (vt<128)

    for (int t=0; t<NSTEPS; ++t){
        if (vt < 128){   // xW[t] slice (bf16, 512 elems) -> xwlds padded [b][j]
            ushort4 v = *reinterpret_cast<const ushort4*>(gp + ((size_t)t*512 + vbid)*512 + vt*4);
            const int b = vt >> 1, j0 = (vt & 1)*4;
            float* xp = &xwlds[vb][b*9 + j0];
            xp[0]=bf2f(v.x); xp[1]=bf2f(v.y); xp[2]=bf2f(v.z); xp[3]=bf2f(v.w);
        }

        const int rs = (t > 0) ? (t-1) : (first ? 256 : NSTEPS-1);
        const float* hc = ring + (size_t)rs*65536 + (size_t)kbase*64;
        float4 pre = *reinterpret_cast<const float4*>(hc + l*4);
        *reinterpret_cast<float4*>(&hstage[vb][w8][0][l*4]) = pre;

        float acc[2][4];
        #pragma unroll
        for (int i2=0;i2<2;++i2){acc[i2][0]=0.f;acc[i2][1]=0.f;acc[i2][2]=0.f;acc[i2][3]=0.f;}

        for (int sc=0; sc<32; ++sc){
            if (sc < 31)
                pre = *reinterpret_cast<const float4*>(hc + (size_t)(sc+1)*256 + l*4);
            const float* hs = hstage[vb][w8][sc&1];
            const float* wl = &Wlds[vb][(size_t)(kbase + sc*4)*8];
            #pragma unroll
            for (int kk=0; kk<4; ++kk){
                float2 hv = *reinterpret_cast<const float2*>(&hs[kk*64 + b0]);
                float4 wv = *reinterpret_cast<const float4*>(&wl[kk*8 + c0]);
                acc[0][0]+=hv.x*wv.x; acc[0][1]+=hv.x*wv.y; acc[0][2]+=hv.x*wv.z; acc[0][3]+=hv.x*wv.w;
                acc[1][0]+=hv.y*wv.x; acc[1][1]+=hv.y*wv.y; acc[1][2]+=hv.y*wv.z; acc[1][3]+=hv.y*wv.w;
            }
            if (sc < 31)
                *reinterpret_cast<float4*>(&hstage[vb][w8][(sc+1)&1][l*4]) = pre;
        }
        #pragma unroll
        for (int bi=0;bi<2;++bi)
            *reinterpret_cast<float4*>(&pacc[vb][w8][(b0+bi)*9 + c0]) =
                make_float4(acc[bi][0],acc[bi][1],acc[bi][2],acc[bi][3]);
        __syncthreads();

        if (vt < 128){   // phase C: one thread per (batch, h-col)
            float gs[4];
            #pragma unroll
            for (int g=0; g<4; ++g){
                const int idx = bq*9 + g*2 + hj;
                float s = xwlds[vb][idx];
                #pragma unroll
                for (int pw=0; pw<8; ++pw) s += pacc[vb][pw][idx];
                gs[g] = s;
            }
            float ig = 1.f/(1.f + __expf(-gs[0]));
            float fg = 1.f/(1.f + __expf(-gs[1]));
            float gg = tanhf(gs[2]);
            float og = 1.f/(1.f + __expf(-gs[3]));
            float c_new = fg * creg + ig * gg;
            float h_new = og * tanhf(c_new);
            creg = c_new;
            hout[vb][bq*2 + hj] = h_new;
            if (last && t == NSTEPS-1){
                const int hcolg = vbid*2 + hj;
                hn[(size_t)bq*1024 + hcolg] = h_new;
                cn[(size_t)bq*1024 + hcolg] = c_new;
            }
        }
        __syncthreads();

        if (vt < 64){   // publish h[t] (64-bit returning swaps) + out write
            const int col = vt >> 5, bp = (vt & 31) << 1;
            float v0 = hout[vb][bp*2 + col];
            float v1 = hout[vb][(bp+1)*2 + col];
            unsigned long long pk =
                ((unsigned long long)__float_as_uint(v1) << 32) | __float_as_uint(v0);
            unsigned long long old = __hip_atomic_exchange(
                reinterpret_cast<unsigned long long*>(
                    ring + (size_t)t*65536 + (vbid*2 + col)*64 + bp),
                pk, __ATOMIC_RELAXED, __HIP_MEMORY_SCOPE_AGENT);
            asm volatile("" :: "v"(old));
            float2 ho; ho.x = hout[vb][vt*2]; ho.y = hout[vb][vt*2+1];
            *reinterpret_cast<float2*>(&out[(size_t)t*65536 + (size_t)vt*1024 + vbid*2]) = ho;
        }
        gridbar(bar, t + 2);   // syncthreads inside drains the swaps first
    }
    if (vt < 128) ctg[vbid*128 + vt] = creg;
}

// ---------------------------------------------------------------------------
extern "C" void kernel_launch(void* const* d_in, const int* in_sizes, int n_in,
                              void* d_out, int out_size, void* d_ws, size_t ws_size,
                              hipStream_t stream)
{
    const float* x    = (const float*)d_in[0];
    const float* Wih0 = (const float*)d_in[1];
    const float* Whh0 = (const float*)d_in[2];
    const float* b0   = (const float*)d_in[3];
    const float* Wih1 = (const float*)d_in[4];
    const float* Whh1 = (const float*)d_in[5];
    const float* b1   = (const float*)d_in[6];

    float* out1 = (float*)d_out;
    float* hn   = out1 + (size_t)NROWS*HDIM;      // [2][64][1024]
    float* cn   = hn + 2*BATCH*HDIM;

    // layer-0 output scratch aliases out1 (safe: each out0 chunk is consumed
    // by the layer-1 GEMM before the layer-1 steps overwrite it).
    float* out0 = out1;

    char* wsb = (char*)d_ws;
    unsigned short* gp    = (unsigned short*)wsb;                      // 134,217,728 B
    unsigned short* WThi0 = (unsigned short*)(wsb + 134217728ull);     //   8,388,608
    unsigned short* WTlo0 = (unsigned short*)(wsb + 142606336ull);     //   8,388,608
    unsigned short* WThi1 = (unsigned short*)(wsb + 150994944ull);     //   8,388,608
    unsigned short* WTlo1 = (unsigned short*)(wsb + 159383552ull);     //   8,388,608
    float*          Whh0r = (float*)(wsb + 167772160ull);              //  16,777,216
    float*          Whh1r = (float*)(wsb + 184549376ull);              //  16,777,216
    float*          ring  = (float*)(wsb + 201326592ull);              //  67,371,008 (257 slots)
    float*          ctg   = (float*)(wsb + 268697600ull);              //     262,144
    unsigned int*   bar   = (unsigned int*)(wsb + 268959744ull);       //     262,144 (4 x 64KB)

    hipMemsetAsync(bar, 0, 262144, stream);
    split_transpose_w<<<dim3(128,32),256,0,stream>>>(Wih0, WThi0, WTlo0);
    split_transpose_w<<<dim3(128,32),256,0,stream>>>(Wih1, WThi1, WTlo1);
    reorder_whh2<<<512,256,0,stream>>>(Whh0, Whh0r);
    reorder_whh2<<<512,256,0,stream>>>(Whh1, Whh1r);

    const float*          Ain [2] = {x, out0};
    const unsigned short* Whi [2] = {WThi0, WThi1};
    const unsigned short* Wlo [2] = {WTlo0, WTlo1};
    const float*          bia [2] = {b0, b1};
    const float*          whr [2] = {Whh0r, Whh1r};
    float*                outp[2] = {out0, out1};

    for (int layer=0; layer<2; ++layer){
        float* hnL = hn + (size_t)layer*BATCH*HDIM;
        float* cnL = cn + (size_t)layer*BATCH*HDIM;
        for (int chunk=0; chunk<2; ++chunk){
            gemm_xw_split<<<4096,256,0,stream>>>(
                Ain[layer] + (size_t)chunk*NSTEPS*BATCH*HDIM,
                Whi[layer], Wlo[layer], bia[layer], gp);

            const unsigned short* gpc = gp;
            const float* wh = whr[layer];
            float* op = outp[layer] + (size_t)chunk*NSTEPS*BATCH*HDIM;
            float* rg = ring; float* cg_ = ctg;
            unsigned int* br = bar + (size_t)(layer*2 + chunk)*16384;
            int first = (chunk == 0), last = (chunk == 1);
            void* args[10] = {(void*)&gpc, (void*)&wh, (void*)&op, (void*)&rg,
                              (void*)&cg_, (void*)&hnL, (void*)&cnL,
                              (void*)&br, (void*)&first, (void*)&last};
            hipLaunchCooperativeKernel(reinterpret_cast<void*>(&lstm_ring3),
                                       dim3(256), dim3(1024), args, 0, stream);
        }
    }
}

// Round 15
// 13430.524 us; speedup vs baseline: 3.0703x; 1.2714x over previous
//
#include <hip/hip_runtime.h>
#include <hip/hip_bf16.h>

#define TSTEPS 512
#define NSTEPS 256          // steps per chunk
#define BATCH  64
#define HDIM   1024
#define NROWS  (TSTEPS*BATCH)   // 32768

typedef __attribute__((ext_vector_type(8))) short bf16x8;
typedef __attribute__((ext_vector_type(4))) float f32x4;

__device__ __forceinline__ unsigned short f2bf(float f){
    unsigned u = __float_as_uint(f);
    u += 0x7fffu + ((u >> 16) & 1u);
    return (unsigned short)(u >> 16);
}
__device__ __forceinline__ float bf2f(unsigned short s){
    return __uint_as_float(((unsigned)s) << 16);
}

// ---------------------------------------------------------------------------
// Contention-free broadcast grid barrier, 256 blocks (r11/r14-proven).
// Private 128B lines; arrival slots region[b*32], release region[8192+b*32].
// h coherence: returning atomic swaps (ack == at L3) + fresh-address reads;
// __syncthreads drains each wave's vmcnt before arrival.
// ---------------------------------------------------------------------------
__device__ __forceinline__ void gridbar(unsigned int* region, unsigned int epoch){
    unsigned int* slots = region;
    unsigned int* rel   = region + 8192;
    __syncthreads();    // all waves' vmem (incl. h swaps) acked at L3
    if (blockIdx.x == 0){
        const int i = threadIdx.x;
        if (i > 0 && i < 256){
            while (__hip_atomic_load(&slots[i*32], __ATOMIC_RELAXED, __HIP_MEMORY_SCOPE_AGENT) < epoch)
                __builtin_amdgcn_s_sleep(2);
        }
        __syncthreads();
        if (i < 256){
            unsigned int old = __hip_atomic_exchange(&rel[i*32], epoch,
                                   __ATOMIC_RELAXED, __HIP_MEMORY_SCOPE_AGENT);
            asm volatile("" :: "v"(old));
        }
    } else {
        if (threadIdx.x == 0){
            unsigned int old = __hip_atomic_exchange(&slots[blockIdx.x*32], epoch,
                                   __ATOMIC_RELAXED, __HIP_MEMORY_SCOPE_AGENT);
            asm volatile("" :: "v"(old));
            while (__hip_atomic_load(&rel[blockIdx.x*32], __ATOMIC_RELAXED, __HIP_MEMORY_SCOPE_AGENT) < epoch)
                __builtin_amdgcn_s_sleep(2);
        }
        __syncthreads();
    }
    asm volatile("" ::: "memory");  // no hoisting ring loads above
}

// ---------------------------------------------------------------------------
// W [1024][4096] fp32 -> WThi/WTlo [4096][1024] bf16 (transpose + split)
// ---------------------------------------------------------------------------
__global__ __launch_bounds__(256)
void split_transpose_w(const float* __restrict__ W,
                       unsigned short* __restrict__ WThi,
                       unsigned short* __restrict__ WTlo)
{
    __shared__ float tile[32][33];
    const int c0 = blockIdx.x * 32;
    const int k0 = blockIdx.y * 32;
    const int tx = threadIdx.x & 31, ty = threadIdx.x >> 5;
    #pragma unroll
    for (int r=0;r<4;++r)
        tile[ty + r*8][tx] = W[(size_t)(k0 + ty + r*8)*4096 + c0 + tx];
    __syncthreads();
    #pragma unroll
    for (int r=0;r<4;++r){
        float v = tile[tx][ty + r*8];
        unsigned short hi = f2bf(v);
        unsigned short lo = f2bf(v - bf2f(hi));
        WThi[(size_t)(c0 + ty + r*8)*1024 + k0 + tx] = hi;
        WTlo[(size_t)(c0 + ty + r*8)*1024 + k0 + tx] = lo;
    }
}

// ---------------------------------------------------------------------------
// W_hh [1024][4096] fp32 -> Wt_hi/Wt_lo [256 bid][16 j][1024 k] bf16 split,
// j = g*4+hj  <->  col = g*1024 + bid*4 + hj   (MFMA B-operand layout)
// ---------------------------------------------------------------------------
__global__ __launch_bounds__(256)
void reorder_whh_t(const float* __restrict__ W,
                   unsigned short* __restrict__ Whi,
                   unsigned short* __restrict__ Wlo)
{
    const int bid = blockIdx.x;
    const int j  = threadIdx.x & 15;
    const int k0 = threadIdx.x >> 4;
    const int col = (j>>2)*1024 + bid*4 + (j&3);
    for (int k = k0; k < 1024; k += 16){
        float v = W[(size_t)k*4096 + col];
        unsigned short hi = f2bf(v);
        unsigned short lo = f2bf(v - bf2f(hi));
        Whi[((size_t)bid*16 + j)*1024 + k] = hi;
        Wlo[((size_t)bid*16 + j)*1024 + k] = lo;
    }
}

// ---------------------------------------------------------------------------
// Split-bf16 MFMA GEMM over one 16384-row chunk (r9-proven, bf16 out):
//   gp[t][bid256][b][16],  j = g*4 + hj,  col = g*1024 + bid*4 + hj
// ---------------------------------------------------------------------------
__global__ __launch_bounds__(256)
void gemm_xw_split(const float* __restrict__ A,
                   const unsigned short* __restrict__ BThi,
                   const unsigned short* __restrict__ BTlo,
                   const float* __restrict__ bias, unsigned short* __restrict__ gp)
{
    __shared__ __align__(16) unsigned short Ahi[128*32];
    __shared__ __align__(16) unsigned short Alo[128*32];
    __shared__ __align__(16) unsigned short Bhi[128*32];
    __shared__ __align__(16) unsigned short Blo[128*32];

    const int tid = threadIdx.x;
    const int w = tid >> 6, l = tid & 63;
    const int bx = blockIdx.x & 31, by = blockIdx.x >> 5;
    const int row0 = by*128, col0 = bx*128;
    const int wrow = (w>>1)*64, wcol = (w&1)*64;

    const int srow  = l >> 2;
    const int skoff = (l & 3) * 8;

    const int arow  = tid >> 1;
    const int akoff = (tid & 1) * 16;
    const float* aptr = A + (size_t)(row0 + arow)*1024 + akoff;

    f32x4 acc[4][4];
    #pragma unroll
    for (int m=0;m<4;++m)
        #pragma unroll
        for (int n=0;n<4;++n)
            acc[m][n] = (f32x4){0.f,0.f,0.f,0.f};

    for (int k0=0; k0<1024; k0+=32){
        #pragma unroll
        for (int c=0;c<2;++c){
            const int i = w*2 + c;
            const unsigned short* gh = BThi + (size_t)(col0 + i*16 + srow)*1024 + k0 + skoff;
            const unsigned short* gl = BTlo + (size_t)(col0 + i*16 + srow)*1024 + k0 + skoff;
            __builtin_amdgcn_global_load_lds((const __attribute__((address_space(1))) void*)gh,
                (__attribute__((address_space(3))) void*)(Bhi + i*512), 16, 0, 0);
            __builtin_amdgcn_global_load_lds((const __attribute__((address_space(1))) void*)gl,
                (__attribute__((address_space(3))) void*)(Blo + i*512), 16, 0, 0);
        }
        {
            float4 x0 = *reinterpret_cast<const float4*>(aptr + k0);
            float4 x1 = *reinterpret_cast<const float4*>(aptr + k0 + 4);
            float4 x2 = *reinterpret_cast<const float4*>(aptr + k0 + 8);
            float4 x3 = *reinterpret_cast<const float4*>(aptr + k0 + 12);
            float xs[16] = {x0.x,x0.y,x0.z,x0.w, x1.x,x1.y,x1.z,x1.w,
                            x2.x,x2.y,x2.z,x2.w, x3.x,x3.y,x3.z,x3.w};
            unsigned short hs[16], ls[16];
            #pragma unroll
            for (int e=0;e<16;++e){
                hs[e] = f2bf(xs[e]);
                ls[e] = f2bf(xs[e] - bf2f(hs[e]));
            }
            #pragma unroll
            for (int q=0;q<4;++q){
                ushort4 h4; h4.x=hs[q*4]; h4.y=hs[q*4+1]; h4.z=hs[q*4+2]; h4.w=hs[q*4+3];
                ushort4 l4; l4.x=ls[q*4]; l4.y=ls[q*4+1]; l4.z=ls[q*4+2]; l4.w=ls[q*4+3];
                *reinterpret_cast<ushort4*>(&Ahi[arow*32 + akoff + q*4]) = h4;
                *reinterpret_cast<ushort4*>(&Alo[arow*32 + akoff + q*4]) = l4;
            }
        }
        __syncthreads();
        bf16x8 afh[4], afl[4], bfh[4], bfl[4];
        #pragma unroll
        for (int m=0;m<4;++m){
            const int off = (wrow + m*16 + (l&15))*32 + (l>>4)*8;
            afh[m] = *reinterpret_cast<const bf16x8*>(&Ahi[off]);
            afl[m] = *reinterpret_cast<const bf16x8*>(&Alo[off]);
        }
        #pragma unroll
        for (int n=0;n<4;++n){
            const int off = (wcol + n*16 + (l&15))*32 + (l>>4)*8;
            bfh[n] = *reinterpret_cast<const bf16x8*>(&Bhi[off]);
            bfl[n] = *reinterpret_cast<const bf16x8*>(&Blo[off]);
        }
        #pragma unroll
        for (int m=0;m<4;++m)
            #pragma unroll
            for (int n=0;n<4;++n){
                acc[m][n] = __builtin_amdgcn_mfma_f32_16x16x32_bf16(afh[m], bfh[n], acc[m][n], 0,0,0);
                acc[m][n] = __builtin_amdgcn_mfma_f32_16x16x32_bf16(afl[m], bfh[n], acc[m][n], 0,0,0);
                acc[m][n] = __builtin_amdgcn_mfma_f32_16x16x32_bf16(afh[m], bfl[n], acc[m][n], 0,0,0);
            }
        __syncthreads();
    }

    #pragma unroll
    for (int n=0;n<4;++n){
        const int n_g = col0 + wcol + n*16 + (l&15);
        const float bv = bias[n_g];
        const int g = n_g >> 10, hcol = n_g & 1023;
        const int bid = hcol >> 2, hj = hcol & 3;
        #pragma unroll
        for (int m=0;m<4;++m){
            #pragma unroll
            for (int r=0;r<4;++r){
                const int m_g = row0 + wrow + m*16 + (l>>4)*4 + r;
                const int t = m_g >> 6, b = m_g & 63;
                gp[(((size_t)t*256 + bid)*64 + b)*16 + g*4 + hj] = f2bf(acc[m][n][r] + bv);
            }
        }
    }
}

// ---------------------------------------------------------------------------
// MFMA recurrence over one 256-step chunk. 256 blocks x 512 threads (8 waves).
// Block owns gate-cols [bid*4, bid*4+4) x 4 gates (16 j). W_hh fragments in
// VGPRs (wave w owns K-range [w*128, w*128+128)). h exchanged as split-bf16
// rings [b][hcol]: write via returning 64-bit swaps, read via plain
// fresh-address loads. Split-bf16 MFMA (hi*hi + lo*hi + hi*lo), fp32 accum.
// ---------------------------------------------------------------------------
__global__ __launch_bounds__(512)
void lstm_mfma(const unsigned short* __restrict__ gp,
               const unsigned short* __restrict__ Whi,
               const unsigned short* __restrict__ Wlo,
               float* __restrict__ out,
               unsigned short* __restrict__ rhi, unsigned short* __restrict__ rlo,
               float* __restrict__ ctg, float* __restrict__ hn, float* __restrict__ cn,
               unsigned int* __restrict__ bar, int first, int last)
{
    __shared__ float pacc[8][64*17];   // 34.8 KB wave-partials [w][b][j(16)+pad]
    __shared__ float xwlds[64*17];     //  4.3 KB xW slice [b][j+pad]
    __shared__ float hout[256];        //  1 KB   h_new [b*4 + hc]

    const int tid  = threadIdx.x;
    const int bidx = blockIdx.x;
    const int w = tid >> 6, l = tid & 63;
    const int kbase = w << 7;            // wave K-range [kbase, kbase+128)

    // W fragments, resident in VGPRs for the whole chunk.
    // Lane l: j = l&15, k-chunk (l>>4)*8 within each 32-k step.
    bf16x8 wfh[4], wfl[4];
    {
        const unsigned short* bh = Whi + ((size_t)bidx*16 + (l&15))*1024 + kbase + (l>>4)*8;
        const unsigned short* bl = Wlo + ((size_t)bidx*16 + (l&15))*1024 + kbase + (l>>4)*8;
        #pragma unroll
        for (int ks=0; ks<4; ++ks){
            wfh[ks] = *reinterpret_cast<const bf16x8*>(bh + ks*32);
            wfl[ks] = *reinterpret_cast<const bf16x8*>(bl + ks*32);
        }
    }

    float creg = 0.f;
    if (!first && tid < 256) creg = ctg[bidx*256 + tid];
    if (first && tid < 64){   // zero slot 256 (h_{-1}) rows=tid, cols bid*4..+3
        unsigned long long o1 = __hip_atomic_exchange(
            reinterpret_cast<unsigned long long*>(rhi + (size_t)256*65536 + tid*1024 + bidx*4),
            0ull, __ATOMIC_RELAXED, __HIP_MEMORY_SCOPE_AGENT);
        unsigned long long o2 = __hip_atomic_exchange(
            reinterpret_cast<unsigned long long*>(rlo + (size_t)256*65536 + tid*1024 + bidx*4),
            0ull, __ATOMIC_RELAXED, __HIP_MEMORY_SCOPE_AGENT);
        asm volatile("" :: "v"(o1), "v"(o2));
    }
    gridbar(bar, 1);

    const int bq = tid & 63;             // phase-C batch
    const int hc = tid >> 6;             // phase-C h-col (tid<256)

    for (int t=0; t<NSTEPS; ++t){
        if (tid < 128){   // xW[t] slice (bf16, 1024 elems) -> xwlds padded
            bf16x8 v = *reinterpret_cast<const bf16x8*>(
                gp + (size_t)t*262144 + (size_t)bidx*1024 + tid*8);
            const int b = tid >> 1, j0 = (tid & 1)*8;
            float* xp = &xwlds[b*17 + j0];
            #pragma unroll
            for (int e=0;e<8;++e) xp[e] = bf2f((unsigned short)v[e]);
        }

        const int rs = (t > 0) ? (t-1) : (first ? 256 : NSTEPS-1);
        const unsigned short* hbh = rhi + (size_t)rs*65536 + kbase + (l>>4)*8;
        const unsigned short* hbl = rlo + (size_t)rs*65536 + kbase + (l>>4)*8;

        f32x4 acc[4];
        #pragma unroll
        for (int mt=0; mt<4; ++mt) acc[mt] = (f32x4){0.f,0.f,0.f,0.f};

        #pragma unroll
        for (int mt=0; mt<4; ++mt){
            const size_t row = (size_t)(mt*16 + (l&15)) * 1024;
            #pragma unroll
            for (int ks=0; ks<4; ++ks){
                bf16x8 ah = *reinterpret_cast<const bf16x8*>(hbh + row + ks*32);
                bf16x8 al = *reinterpret_cast<const bf16x8*>(hbl + row + ks*32);
                acc[mt] = __builtin_amdgcn_mfma_f32_16x16x32_bf16(ah, wfh[ks], acc[mt], 0,0,0);
                acc[mt] = __builtin_amdgcn_mfma_f32_16x16x32_bf16(al, wfh[ks], acc[mt], 0,0,0);
                acc[mt] = __builtin_amdgcn_mfma_f32_16x16x32_bf16(ah, wfl[ks], acc[mt], 0,0,0);
            }
        }
        #pragma unroll
        for (int mt=0; mt<4; ++mt){
            #pragma unroll
            for (int r=0; r<4; ++r){
                const int m = mt*16 + (l>>4)*4 + r;   // batch row
                pacc[w][m*17 + (l&15)] = acc[mt][r];
            }
        }
        __syncthreads();

        if (tid < 256){   // phase C: one thread per (batch, h-col)
            float gs[4];
            #pragma unroll
            for (int g=0; g<4; ++g){
                const int idx = bq*17 + g*4 + hc;
                float s = xwlds[idx];
                #pragma unroll
                for (int pw=0; pw<8; ++pw) s += pacc[pw][idx];
                gs[g] = s;
            }
            float ig = 1.f/(1.f + __expf(-gs[0]));
            float fg = 1.f/(1.f + __expf(-gs[1]));
            float gg = tanhf(gs[2]);
            float og = 1.f/(1.f + __expf(-gs[3]));
            float c_new = fg * creg + ig * gg;
            float h_new = og * tanhf(c_new);
            creg = c_new;
            hout[bq*4 + hc] = h_new;
            if (last && t == NSTEPS-1){
                const int hcolg = bidx*4 + hc;
                hn[(size_t)bq*1024 + hcolg] = h_new;
                cn[(size_t)bq*1024 + hcolg] = c_new;
            }
        }
        __syncthreads();

        if (tid < 64){   // publish h[t] split-bf16 (returning swaps) + out
            const int b = tid;
            float h0 = hout[b*4+0], h1 = hout[b*4+1], h2 = hout[b*4+2], h3 = hout[b*4+3];
            unsigned short p0 = f2bf(h0), p1 = f2bf(h1), p2 = f2bf(h2), p3 = f2bf(h3);
            unsigned short q0 = f2bf(h0 - bf2f(p0)), q1 = f2bf(h1 - bf2f(p1));
            unsigned short q2 = f2bf(h2 - bf2f(p2)), q3 = f2bf(h3 - bf2f(p3));
            unsigned long long phi = (unsigned long long)p0 | ((unsigned long long)p1<<16)
                                   | ((unsigned long long)p2<<32) | ((unsigned long long)p3<<48);
            unsigned long long plo = (unsigned long long)q0 | ((unsigned long long)q1<<16)
                                   | ((unsigned long long)q2<<32) | ((unsigned long long)q3<<48);
            unsigned long long o1 = __hip_atomic_exchange(
                reinterpret_cast<unsigned long long*>(rhi + (size_t)t*65536 + b*1024 + bidx*4),
                phi, __ATOMIC_RELAXED, __HIP_MEMORY_SCOPE_AGENT);
            unsigned long long o2 = __hip_atomic_exchange(
                reinterpret_cast<unsigned long long*>(rlo + (size_t)t*65536 + b*1024 + bidx*4),
                plo, __ATOMIC_RELAXED, __HIP_MEMORY_SCOPE_AGENT);
            asm volatile("" :: "v"(o1), "v"(o2));
            *reinterpret_cast<float4*>(&out[(size_t)t*65536 + (size_t)b*1024 + bidx*4]) =
                make_float4(h0, h1, h2, h3);
        }
        gridbar(bar, t + 2);   // syncthreads inside drains the swaps first
    }
    if (tid < 256) ctg[bidx*256 + tid] = creg;
}

// ---------------------------------------------------------------------------
extern "C" void kernel_launch(void* const* d_in, const int* in_sizes, int n_in,
                              void* d_out, int out_size, void* d_ws, size_t ws_size,
                              hipStream_t stream)
{
    const float* x    = (const float*)d_in[0];
    const float* Wih0 = (const float*)d_in[1];
    const float* Whh0 = (const float*)d_in[2];
    const float* b0   = (const float*)d_in[3];
    const float* Wih1 = (const float*)d_in[4];
    const float* Whh1 = (const float*)d_in[5];
    const float* b1   = (const float*)d_in[6];

    float* out1 = (float*)d_out;
    float* hn   = out1 + (size_t)NROWS*HDIM;      // [2][64][1024]
    float* cn   = hn + 2*BATCH*HDIM;

    // layer-0 output scratch aliases out1 (safe: each out0 chunk is consumed
    // by the layer-1 GEMM before the layer-1 steps overwrite it).
    float* out0 = out1;

    char* wsb = (char*)d_ws;
    unsigned short* gp    = (unsigned short*)wsb;                      // 134,217,728
    unsigned short* WThi0 = (unsigned short*)(wsb + 134217728ull);     //   8,388,608
    unsigned short* WTlo0 = (unsigned short*)(wsb + 142606336ull);     //   8,388,608
    unsigned short* WThi1 = (unsigned short*)(wsb + 150994944ull);     //   8,388,608
    unsigned short* WTlo1 = (unsigned short*)(wsb + 159383552ull);     //   8,388,608
    unsigned short* Wthi0 = (unsigned short*)(wsb + 167772160ull);     //   8,388,608
    unsigned short* Wtlo0 = (unsigned short*)(wsb + 176160768ull);     //   8,388,608
    unsigned short* Wthi1 = (unsigned short*)(wsb + 184549376ull);     //   8,388,608
    unsigned short* Wtlo1 = (unsigned short*)(wsb + 192937984ull);     //   8,388,608
    unsigned short* rhi   = (unsigned short*)(wsb + 201326592ull);     //  33,685,504 (257 slots)
    unsigned short* rlo   = (unsigned short*)(wsb + 235012096ull);     //  33,685,504
    float*          ctg   = (float*)(wsb + 268697600ull);              //     262,144
    unsigned int*   bar   = (unsigned int*)(wsb + 268959744ull);       //     262,144 (4 x 64KB)

    hipMemsetAsync(bar, 0, 262144, stream);
    split_transpose_w<<<dim3(128,32),256,0,stream>>>(Wih0, WThi0, WTlo0);
    split_transpose_w<<<dim3(128,32),256,0,stream>>>(Wih1, WThi1, WTlo1);
    reorder_whh_t<<<256,256,0,stream>>>(Whh0, Wthi0, Wtlo0);
    reorder_whh_t<<<256,256,0,stream>>>(Whh1, Wthi1, Wtlo1);

    const float*          Ain [2] = {x, out0};
    const unsigned short* Whi [2] = {WThi0, WThi1};
    const unsigned short* Wlo [2] = {WTlo0, WTlo1};
    const float*          bia [2] = {b0, b1};
    const unsigned short* wth [2] = {Wthi0, Wthi1};
    const unsigned short* wtl [2] = {Wtlo0, Wtlo1};
    float*                outp[2] = {out0, out1};

    for (int layer=0; layer<2; ++layer){
        float* hnL = hn + (size_t)layer*BATCH*HDIM;
        float* cnL = cn + (size_t)layer*BATCH*HDIM;
        for (int chunk=0; chunk<2; ++chunk){
            gemm_xw_split<<<4096,256,0,stream>>>(
                Ain[layer] + (size_t)chunk*NSTEPS*BATCH*HDIM,
                Whi[layer], Wlo[layer], bia[layer], gp);

            const unsigned short* gpc = gp;
            const unsigned short* wh = wth[layer];
            const unsigned short* wl = wtl[layer];
            float* op = outp[layer] + (size_t)chunk*NSTEPS*BATCH*HDIM;
            unsigned short* r1 = rhi; unsigned short* r2 = rlo;
            float* cg_ = ctg;
            unsigned int* br = bar + (size_t)(layer*2 + chunk)*16384;
            int first = (chunk == 0), last = (chunk == 1);
            void* args[12] = {(void*)&gpc, (void*)&wh, (void*)&wl, (void*)&op,
                              (void*)&r1, (void*)&r2, (void*)&cg_,
                              (void*)&hnL, (void*)&cnL,
                              (void*)&br, (void*)&first, (void*)&last};
            hipLaunchCooperativeKernel(reinterpret_cast<void*>(&lstm_mfma),
                                       dim3(256), dim3(512), args, 0, stream);
        }
    }
}